// Round 3
// baseline (835.136 us; speedup 1.0000x reference)
//
#include <hip/hip_runtime.h>
#include <hip/hip_cooperative_groups.h>
#include <math.h>

namespace cg = cooperative_groups;

// Problem constants
#define B_ 4
#define T_ 256
#define N_ 8
#define D_ 128
#define NH_ 4
#define HD_ 32
#define LENC_ 2
#define MLPH_ 32
#define NL_SCALE_ 0.1f

typedef __bf16 bf16;
typedef __attribute__((ext_vector_type(2))) __bf16 bf16x2;
typedef __attribute__((ext_vector_type(4))) __bf16 bf16x4;
typedef __attribute__((ext_vector_type(8))) __bf16 bf16x8;
typedef __attribute__((ext_vector_type(4))) float f32x4;

__device__ __forceinline__ f32x4 pv_mfma16(bf16x4 a, bf16x4 b, f32x4 c) {
#if __has_builtin(__builtin_amdgcn_mfma_f32_16x16x16_bf16)
    return __builtin_amdgcn_mfma_f32_16x16x16_bf16(a, b, c, 0, 0, 0);
#else
    typedef __attribute__((ext_vector_type(4))) short s4;
    union U { bf16x4 h; s4 s; };
    U ua, ub; ua.h = a; ub.h = b;
    return __builtin_amdgcn_mfma_f32_16x16x16bf16_1k(ua.s, ub.s, c, 0, 0, 0);
#endif
}

__device__ __forceinline__ float gelu_f(float x) {
    return 0.5f * x * (1.0f + erff(x * 0.7071067811865476f));
}

__device__ __forceinline__ float exp2_fast(float x) {
#if __has_builtin(__builtin_amdgcn_exp2f)
    return __builtin_amdgcn_exp2f(x);
#else
    return __expf(x * 0.6931471805599453f);
#endif
}

// log2(e) / sqrt(32) — folded softmax scale for exp2.
#define SCALE_LOG2E 0.25503486f

// ---------------------------------------------------------------------------
// Parameter block for the fused cooperative kernel.
struct KParams {
    const float *vs, *semb, *r5, *A55, *bl_bias;
    const float *nlW1, *nlb1, *nlW2, *nlb2;
    const float *mlpW1, *mlpb1, *mlpb2, *mlplng, *mlplnb;
    const float *eqkvW, *eqkvb, *eoutW, *eoutb, *eln1g, *eln1b;
    const float *eff1, *effb1, *eff2, *effb2, *eln2g, *eln2b;
    const float *caWq, *cabq, *caWk, *cabk, *caWv, *cabv, *caWo, *cabo;
    const float *cln1g, *cln1b, *cff1, *cffb1, *cff2, *cffb2, *cln2g, *cln2b;
    float* out;
    float* b1w; float* X0; bf16* Wpk; float* bpk;
    bf16* X0h; bf16* sembh; bf16* ATTh;
    bf16 *Qh, *Kh, *Vth;
};

// LDS union across phases (max = attn: 42496 B).
struct SMem {
    union {
        struct { float F[16][16]; bf16 H1[16][136]; float S[16][132]; } mlp;
        struct { bf16 Ql[64][40]; bf16 Kl[256][40]; bf16 Vt[32][264]; } attn;
        struct { float S[16][132]; float X1f[16][132]; bf16 X1h[16][136]; bf16 H[16][264]; } etail;
        struct { float S[16][132]; bf16 s1h[16][136]; bf16 H[16][520]; } ctail;
        struct { float O[4][64][36]; float L[4][64]; } ma;
    };
};

// ---------------------------------------------------------------------------
// Phase 0: weight pack + sembh + bpk + b1 baseline (grid-stride over items).
__device__ __forceinline__ void ph_prep(const KParams& p) {
    const int NB1 = B_ * (T_ - 1);            // 1020
    const int NPK = 540672;
    const int NSB = 1048576;
    const int TOT = NB1 + NPK + NSB + 256;
    for (int it = blockIdx.x * 256 + threadIdx.x; it < TOT; it += 512 * 256) {
        if (it < NB1) {
            int idx = it;
            int b = idx / (T_ - 1), t = idx % (T_ - 1);
            float x[N_];
            for (int n = 0; n < N_; n++) x[n] = p.vs[(b * T_ + t) * N_ + n];
            float h[MLPH_];
            for (int j = 0; j < MLPH_; j++) {
                float a = p.nlb1[j];
                for (int n = 0; n < N_; n++) a += x[n] * p.nlW1[j * N_ + n];
                h[j] = gelu_f(a);
            }
            for (int m = 0; m < N_; m++) {
                float lin = p.r5[m];
                for (int n = 0; n < N_; n++) lin += x[n] * p.A55[m * N_ + n];
                float nl = p.nlb2[m];
                for (int j = 0; j < MLPH_; j++) nl += h[j] * p.nlW2[m * MLPH_ + j];
                p.b1w[idx * N_ + m] = lin + NL_SCALE_ * nl + p.bl_bias[m];
            }
        } else if (it < NB1 + NPK) {
            int i = it - NB1;
            const float* src; int off;
            if      (i < 98304)  { src = p.eqkvW; off = 0; }
            else if (i < 131072) { src = p.eoutW; off = 98304; }
            else if (i < 196608) { src = p.eff1;  off = 131072; }
            else if (i < 262144) { src = p.eff2;  off = 196608; }
            else if (i < 278528) { src = p.caWq;  off = 262144; }
            else if (i < 294912) { src = p.caWk;  off = 278528; }
            else if (i < 311296) { src = p.caWv;  off = 294912; }
            else if (i < 327680) { src = p.caWo;  off = 311296; }
            else if (i < 458752) { src = p.cff1;  off = 327680; }
            else if (i < 524288) { src = p.cff2;  off = 458752; }
            else                 { src = p.mlpW1 - 524288 + 524288, src = p.out, src = nullptr; }
            if (i < 524288) {
                p.Wpk[i] = (bf16)src[i - off];
            } else {
                // mlp_W2 tail
                extern const float* _dummy_;
                p.Wpk[i] = (bf16)0.0f;  // overwritten below
            }
        } else if (it < NB1 + NPK + NSB) {
            int j = it - NB1 - NPK;
            p.sembh[j] = (bf16)p.semb[j];
        } else {
            int t = it - NB1 - NPK - NSB;
            p.bpk[t] = (t < 128) ? p.cabk[t] : p.cabv[t - 128];
        }
    }
}

// mlp_W2 pack handled separately (needs its own source pointer).
__device__ __forceinline__ void ph_prep_mlpw2(const KParams& p, const float* mlpW2) {
    for (int i = blockIdx.x * 256 + threadIdx.x; i < 16384; i += 512 * 256)
        p.Wpk[524288 + i] = (bf16)mlpW2[i];
}

// ---------------------------------------------------------------------------
// Phase 1: features + mlp1 + W2 GEMM + gelu + LN + PE + transpose write.
__device__ __forceinline__ void ph_mlp(const KParams& p, SMem& sm) {
    auto& F  = sm.mlp.F;
    auto& H1 = sm.mlp.H1;
    auto& S  = sm.mlp.S;
    const bf16* W2 = p.Wpk + 524288;
    int tid = threadIdx.x;
    int blk = blockIdx.x;
    {
        int row = tid >> 4, feat = tid & 15;
        int grow = blk * 16 + row;
        int b = grow >> 11, t = (grow >> 3) & 255, n = grow & 7;
        const int SC[4] = {1, 2, 3, 5};
        int lag = feat >> 2, si = feat & 3, k = SC[si];
        int tp = t - lag;
        float r = 0.0f;
        if (tp >= 0 && tp < T_ - k) {
            float lx0 = logf(fmaxf(p.vs[(b * T_ + tp) * N_ + n], 1e-6f));
            float lx1 = logf(fmaxf(p.vs[(b * T_ + tp + k) * N_ + n], 1e-6f));
            float a = lx1 - lx0;
            a = fminf(fmaxf(a, -2.5f * (float)k), 2.0f * (float)k);
            float bk = 0.0f;
            for (int i = 0; i < k; i++) bk += p.b1w[(b * (T_ - 1) + tp + i) * N_ + n];
            r = a - bk;
        }
        F[row][feat] = r;
    }
    __syncthreads();
    {
        int row = tid >> 4, cg_ = tid & 15;
        float f[16];
#pragma unroll
        for (int c = 0; c < 16; c++) f[c] = F[row][c];
#pragma unroll
        for (int j = 0; j < 8; j++) {
            int d = cg_ * 8 + j;
            float a = p.mlpb1[d];
            const float* w = p.mlpW1 + d * 16;
#pragma unroll
            for (int c = 0; c < 16; c++) a += f[c] * w[c];
            H1[row][d] = (bf16)gelu_f(a);
        }
    }
    __syncthreads();
    int w = tid >> 6, lane = tid & 63;
    int c = lane & 15, gq = lane >> 4;
    int cb = w * 32;
    const f32x4 zero = {0, 0, 0, 0};
    {
        const bf16x8* Wp0 = (const bf16x8*)(W2 + (size_t)(cb + c) * 128) + gq;
        const bf16x8* Wp1 = (const bf16x8*)(W2 + (size_t)(cb + 16 + c) * 128) + gq;
        f32x4 a0 = zero, a1 = zero;
#pragma unroll
        for (int k = 0; k < 4; k++) {
            bf16x8 av = *(const bf16x8*)&H1[c][k * 32 + gq * 8];
            a0 = __builtin_amdgcn_mfma_f32_16x16x32_bf16(av, Wp0[k * 4], a0, 0, 0, 0);
            a1 = __builtin_amdgcn_mfma_f32_16x16x32_bf16(av, Wp1[k * 4], a1, 0, 0, 0);
        }
#pragma unroll
        for (int r = 0; r < 4; r++) {
            S[gq * 4 + r][cb + c]      = gelu_f(a0[r] + p.mlpb2[cb + c]);
            S[gq * 4 + r][cb + 16 + c] = gelu_f(a1[r] + p.mlpb2[cb + 16 + c]);
        }
    }
    __syncthreads();
    {
        int row = tid >> 4, cg_ = tid & 15;
        int grow = blk * 16 + row;
        int b = grow >> 11, t = (grow >> 3) & 255, n = grow & 7;
        int orow = (b * 8 + n) * 256 + t;
        float v[8];
#pragma unroll
        for (int j = 0; j < 8; j++) v[j] = S[row][cg_ * 8 + j];
        float s = 0.0f;
#pragma unroll
        for (int j = 0; j < 8; j++) s += v[j];
        s += __shfl_xor(s, 1); s += __shfl_xor(s, 2);
        s += __shfl_xor(s, 4); s += __shfl_xor(s, 8);
        float mean = s * (1.0f / 128.0f);
        float vs2 = 0.0f;
#pragma unroll
        for (int j = 0; j < 8; j++) { float d = v[j] - mean; vs2 += d * d; }
        vs2 += __shfl_xor(vs2, 1); vs2 += __shfl_xor(vs2, 2);
        vs2 += __shfl_xor(vs2, 4); vs2 += __shfl_xor(vs2, 8);
        float rstd = rsqrtf(vs2 * (1.0f / 128.0f) + 1e-5f);
        float y[8];
#pragma unroll
        for (int j = 0; j < 8; j++) {
            int col = cg_ * 8 + j;
            y[j] = (v[j] - mean) * rstd * p.mlplng[col] + p.mlplnb[col];
        }
#pragma unroll
        for (int jj = 0; jj < 4; jj++) {
            int j2 = cg_ * 4 + jj;
            float freq = expf((float)(2 * j2) * (-9.210340371976184f / 128.0f));
            float ang = (float)t * freq;
            y[2 * jj] += sinf(ang);
            y[2 * jj + 1] += cosf(ang);
        }
        float4* of = (float4*)(p.X0 + (size_t)orow * 128 + cg_ * 8);
        of[0] = (float4){y[0], y[1], y[2], y[3]};
        of[1] = (float4){y[4], y[5], y[6], y[7]};
        bf16x8 o;
#pragma unroll
        for (int e = 0; e < 8; e++) o[e] = (bf16)y[e];
        *(bf16x8*)(p.X0h + (size_t)orow * 128 + cg_ * 8) = o;
    }
}

// ---------------------------------------------------------------------------
// Encoder QKV + attention (R0 layout: block = (seq-head, query-quarter)).
__device__ __forceinline__ void ph_attn(const KParams& p, SMem& sm, int layer) {
    const bf16* Wqkv = p.Wpk + layer * 49152;
    const float* bqkv = p.eqkvb + layer * 384;
    auto& Ql = sm.attn.Ql;
    auto& Kl = sm.attn.Kl;
    auto& Vt = sm.attn.Vt;
    int sh = blockIdx.x & 127;
    int qh = blockIdx.x >> 7;
    int s = sh >> 2, h = sh & 3;
    int tid = threadIdx.x;
    int wv = tid >> 6, lane = tid & 63;
    int c = lane & 15, g = lane >> 4;
    const f32x4 zero = {0, 0, 0, 0};

    const bf16* Wq0 = Wqkv + (size_t)(h * 32 + c) * 128;
    const bf16* Wq1 = Wqkv + (size_t)(h * 32 + 16 + c) * 128;
    const bf16* Wk0 = Wqkv + (size_t)(128 + h * 32 + c) * 128;
    const bf16* Wk1 = Wqkv + (size_t)(128 + h * 32 + 16 + c) * 128;
    const bf16* Wv0 = Wqkv + (size_t)(256 + h * 32 + c) * 128;
    const bf16* Wv1 = Wqkv + (size_t)(256 + h * 32 + 16 + c) * 128;
    float bq0 = bqkv[h * 32 + c], bq1 = bqkv[h * 32 + 16 + c];
    float bk0 = bqkv[128 + h * 32 + c], bk1 = bqkv[128 + h * 32 + 16 + c];
    float bv0 = bqkv[256 + h * 32 + c], bv1 = bqkv[256 + h * 32 + 16 + c];

#pragma unroll
    for (int rb = 0; rb < 4; rb++) {
        int row0 = wv * 64 + rb * 16;
        const bf16x8* Ap = (const bf16x8*)(p.X0h + (size_t)(s * 256 + row0 + c) * 128) + g;
        f32x4 ak0 = zero, ak1 = zero, av0 = zero, av1 = zero;
#pragma unroll
        for (int k = 0; k < 4; k++) {
            bf16x8 av = Ap[k * 4];
            ak0 = __builtin_amdgcn_mfma_f32_16x16x32_bf16(av, *((const bf16x8*)Wk0 + k * 4 + g), ak0, 0, 0, 0);
            ak1 = __builtin_amdgcn_mfma_f32_16x16x32_bf16(av, *((const bf16x8*)Wk1 + k * 4 + g), ak1, 0, 0, 0);
            av0 = __builtin_amdgcn_mfma_f32_16x16x32_bf16(av, *((const bf16x8*)Wv0 + k * 4 + g), av0, 0, 0, 0);
            av1 = __builtin_amdgcn_mfma_f32_16x16x32_bf16(av, *((const bf16x8*)Wv1 + k * 4 + g), av1, 0, 0, 0);
        }
        int lr = row0 + g * 4;
#pragma unroll
        for (int i = 0; i < 4; i++) {
            Kl[lr + i][c] = (bf16)(ak0[i] + bk0);
            Kl[lr + i][16 + c] = (bf16)(ak1[i] + bk1);
            Vt[c][lr + i] = (bf16)(av0[i] + bv0);
            Vt[16 + c][lr + i] = (bf16)(av1[i] + bv1);
        }
    }
    {
        int row0q = wv * 16;
        const bf16x8* Ap = (const bf16x8*)(
            p.X0h + (size_t)(s * 256 + qh * 64 + row0q + c) * 128) + g;
        f32x4 aq0 = zero, aq1 = zero;
#pragma unroll
        for (int k = 0; k < 4; k++) {
            bf16x8 av = Ap[k * 4];
            aq0 = __builtin_amdgcn_mfma_f32_16x16x32_bf16(av, *((const bf16x8*)Wq0 + k * 4 + g), aq0, 0, 0, 0);
            aq1 = __builtin_amdgcn_mfma_f32_16x16x32_bf16(av, *((const bf16x8*)Wq1 + k * 4 + g), aq1, 0, 0, 0);
        }
        int lr = row0q + g * 4;
#pragma unroll
        for (int i = 0; i < 4; i++) {
            Ql[lr + i][c] = (bf16)(aq0[i] + bq0);
            Ql[lr + i][16 + c] = (bf16)(aq1[i] + bq1);
        }
    }
    __syncthreads();

    int q0l = wv * 16;
    bf16x8 bqv = *(const bf16x8*)&Ql[q0l + c][g * 8];
    f32x4 oT0 = zero, oT1 = zero;
    float lsum = 0.0f;
#pragma unroll
    for (int t = 0; t < 8; t++) {
        int k0 = t * 32;
        bf16x8 ka = *(const bf16x8*)&Kl[k0 + c][g * 8];
        bf16x8 kb = *(const bf16x8*)&Kl[k0 + 16 + c][g * 8];
        bf16x4 va0 = *(const bf16x4*)&Vt[c][k0 + g * 4];
        bf16x4 va1 = *(const bf16x4*)&Vt[c][k0 + 16 + g * 4];
        bf16x4 vb0 = *(const bf16x4*)&Vt[16 + c][k0 + g * 4];
        bf16x4 vb1 = *(const bf16x4*)&Vt[16 + c][k0 + 16 + g * 4];
        f32x4 s0 = __builtin_amdgcn_mfma_f32_16x16x32_bf16(ka, bqv, zero, 0, 0, 0);
        f32x4 s1 = __builtin_amdgcn_mfma_f32_16x16x32_bf16(kb, bqv, zero, 0, 0, 0);
        bf16x4 p0, p1;
#pragma unroll
        for (int r = 0; r < 4; r++) {
            float e0 = exp2_fast(s0[r] * SCALE_LOG2E);
            float e1 = exp2_fast(s1[r] * SCALE_LOG2E);
            lsum += e0 + e1;
            p0[r] = (bf16)e0;
            p1[r] = (bf16)e1;
        }
        oT0 = pv_mfma16(va0, p0, oT0);
        oT0 = pv_mfma16(va1, p1, oT0);
        oT1 = pv_mfma16(vb0, p0, oT1);
        oT1 = pv_mfma16(vb1, p1, oT1);
    }
    {
        float sm2 = lsum;
        sm2 += __shfl_xor(sm2, 16);
        sm2 += __shfl_xor(sm2, 32);
        float inv = 1.0f / sm2;
        size_t rbase = ((size_t)s * 256 + qh * 64 + q0l + c) * 128 + h * 32;
#pragma unroll
        for (int r = 0; r < 4; r++) {
            p.ATTh[rbase + g * 4 + r] = (bf16)(oT0[r] * inv);
            p.ATTh[rbase + 16 + g * 4 + r] = (bf16)(oT1[r] * inv);
        }
    }
}

// ---------------------------------------------------------------------------
// Encoder tail.
__device__ __forceinline__ void ph_etail(const KParams& p, SMem& sm, int layer) {
    const bf16* Wo = p.Wpk + 98304 + layer * 16384;
    const float* bo = p.eoutb + layer * 128;
    const float* g1 = p.eln1g + layer * 128;
    const float* be1 = p.eln1b + layer * 128;
    const bf16* W1 = p.Wpk + 131072 + layer * 32768;
    const float* bf1 = p.effb1 + layer * 256;
    const bf16* W2 = p.Wpk + 196608 + layer * 32768;
    const float* bf2 = p.effb2 + layer * 128;
    const float* g2 = p.eln2g + layer * 128;
    const float* be2 = p.eln2b + layer * 128;
    auto& S = sm.etail.S;
    auto& X1f = sm.etail.X1f;
    auto& X1h = sm.etail.X1h;
    auto& H = sm.etail.H;
    int tid = threadIdx.x;
    int w = tid >> 6, lane = tid & 63;
    int c = lane & 15, gq = lane >> 4;
    int blk = blockIdx.x;
    const f32x4 zero = {0, 0, 0, 0};

    {
        int cb = w * 32;
        const bf16x8* Ap  = (const bf16x8*)(p.ATTh + (size_t)(blk * 16 + c) * 128) + gq;
        const bf16x8* Wp0 = (const bf16x8*)(Wo + (size_t)(cb + c) * 128) + gq;
        const bf16x8* Wp1 = (const bf16x8*)(Wo + (size_t)(cb + 16 + c) * 128) + gq;
        f32x4 a0 = zero, a1 = zero;
#pragma unroll
        for (int k = 0; k < 4; k++) {
            bf16x8 av = Ap[k * 4];
            a0 = __builtin_amdgcn_mfma_f32_16x16x32_bf16(av, Wp0[k * 4], a0, 0, 0, 0);
            a1 = __builtin_amdgcn_mfma_f32_16x16x32_bf16(av, Wp1[k * 4], a1, 0, 0, 0);
        }
#pragma unroll
        for (int r = 0; r < 4; r++) {
            S[gq * 4 + r][cb + c] = a0[r] + bo[cb + c];
            S[gq * 4 + r][cb + 16 + c] = a1[r] + bo[cb + 16 + c];
        }
    }
    __syncthreads();
    {
        int row = tid >> 4, cg_ = tid & 15;
        float v[8];
        const float4* rp = (const float4*)(p.X0 + (size_t)(blk * 16 + row) * 128 + cg_ * 8);
        float4 r0 = rp[0], r1 = rp[1];
        v[0] = S[row][cg_ * 8 + 0] + r0.x; v[1] = S[row][cg_ * 8 + 1] + r0.y;
        v[2] = S[row][cg_ * 8 + 2] + r0.z; v[3] = S[row][cg_ * 8 + 3] + r0.w;
        v[4] = S[row][cg_ * 8 + 4] + r1.x; v[5] = S[row][cg_ * 8 + 5] + r1.y;
        v[6] = S[row][cg_ * 8 + 6] + r1.z; v[7] = S[row][cg_ * 8 + 7] + r1.w;
        float s = 0.0f;
#pragma unroll
        for (int j = 0; j < 8; j++) s += v[j];
        s += __shfl_xor(s, 1); s += __shfl_xor(s, 2);
        s += __shfl_xor(s, 4); s += __shfl_xor(s, 8);
        float mean = s * (1.0f / 128.0f);
        float vs = 0.0f;
#pragma unroll
        for (int j = 0; j < 8; j++) { float d = v[j] - mean; vs += d * d; }
        vs += __shfl_xor(vs, 1); vs += __shfl_xor(vs, 2);
        vs += __shfl_xor(vs, 4); vs += __shfl_xor(vs, 8);
        float rstd = rsqrtf(vs * (1.0f / 128.0f) + 1e-5f);
#pragma unroll
        for (int j = 0; j < 8; j++) {
            int col = cg_ * 8 + j;
            float y = (v[j] - mean) * rstd * g1[col] + be1[col];
            X1f[row][col] = y;
            X1h[row][col] = (bf16)y;
        }
    }
    __syncthreads();
    {
        int cb2 = w * 64;
        bf16x8 af[4];
#pragma unroll
        for (int k = 0; k < 4; k++)
            af[k] = *(const bf16x8*)&X1h[c][k * 32 + gq * 8];
        const bf16x8* Wp0 = (const bf16x8*)(W1 + (size_t)(cb2 + c) * 128) + gq;
        const bf16x8* Wp1 = (const bf16x8*)(W1 + (size_t)(cb2 + 16 + c) * 128) + gq;
        const bf16x8* Wp2 = (const bf16x8*)(W1 + (size_t)(cb2 + 32 + c) * 128) + gq;
        const bf16x8* Wp3 = (const bf16x8*)(W1 + (size_t)(cb2 + 48 + c) * 128) + gq;
        f32x4 a0 = zero, a1 = zero, a2 = zero, a3 = zero;
#pragma unroll
        for (int k = 0; k < 4; k++) {
            a0 = __builtin_amdgcn_mfma_f32_16x16x32_bf16(af[k], Wp0[k * 4], a0, 0, 0, 0);
            a1 = __builtin_amdgcn_mfma_f32_16x16x32_bf16(af[k], Wp1[k * 4], a1, 0, 0, 0);
            a2 = __builtin_amdgcn_mfma_f32_16x16x32_bf16(af[k], Wp2[k * 4], a2, 0, 0, 0);
            a3 = __builtin_amdgcn_mfma_f32_16x16x32_bf16(af[k], Wp3[k * 4], a3, 0, 0, 0);
        }
#pragma unroll
        for (int r = 0; r < 4; r++) {
            H[gq * 4 + r][cb2 + c]      = (bf16)gelu_f(a0[r] + bf1[cb2 + c]);
            H[gq * 4 + r][cb2 + 16 + c] = (bf16)gelu_f(a1[r] + bf1[cb2 + 16 + c]);
            H[gq * 4 + r][cb2 + 32 + c] = (bf16)gelu_f(a2[r] + bf1[cb2 + 32 + c]);
            H[gq * 4 + r][cb2 + 48 + c] = (bf16)gelu_f(a3[r] + bf1[cb2 + 48 + c]);
        }
    }
    __syncthreads();
    {
        int cb = w * 32;
        bf16x8 af[8];
#pragma unroll
        for (int k = 0; k < 8; k++)
            af[k] = *(const bf16x8*)&H[c][k * 32 + gq * 8];
        const bf16x8* Wp0 = (const bf16x8*)(W2 + (size_t)(cb + c) * 256) + gq;
        const bf16x8* Wp1 = (const bf16x8*)(W2 + (size_t)(cb + 16 + c) * 256) + gq;
        f32x4 a0 = zero, a1 = zero;
#pragma unroll
        for (int k = 0; k < 8; k++) {
            a0 = __builtin_amdgcn_mfma_f32_16x16x32_bf16(af[k], Wp0[k * 4], a0, 0, 0, 0);
            a1 = __builtin_amdgcn_mfma_f32_16x16x32_bf16(af[k], Wp1[k * 4], a1, 0, 0, 0);
        }
#pragma unroll
        for (int r = 0; r < 4; r++) {
            S[gq * 4 + r][cb + c] = a0[r] + bf2[cb + c];
            S[gq * 4 + r][cb + 16 + c] = a1[r] + bf2[cb + 16 + c];
        }
    }
    __syncthreads();
    {
        int row = tid >> 4, cg_ = tid & 15;
        float v[8];
#pragma unroll
        for (int j = 0; j < 8; j++)
            v[j] = S[row][cg_ * 8 + j] + X1f[row][cg_ * 8 + j];
        float s = 0.0f;
#pragma unroll
        for (int j = 0; j < 8; j++) s += v[j];
        s += __shfl_xor(s, 1); s += __shfl_xor(s, 2);
        s += __shfl_xor(s, 4); s += __shfl_xor(s, 8);
        float mean = s * (1.0f / 128.0f);
        float vs = 0.0f;
#pragma unroll
        for (int j = 0; j < 8; j++) { float d = v[j] - mean; vs += d * d; }
        vs += __shfl_xor(vs, 1); vs += __shfl_xor(vs, 2);
        vs += __shfl_xor(vs, 4); vs += __shfl_xor(vs, 8);
        float rstd = rsqrtf(vs * (1.0f / 128.0f) + 1e-5f);
        size_t grow = (size_t)(blk * 16 + row);
        float y[8];
#pragma unroll
        for (int j = 0; j < 8; j++) {
            int col = cg_ * 8 + j;
            y[j] = (v[j] - mean) * rstd * g2[col] + be2[col];
        }
        float4* of = (float4*)(p.X0 + grow * 128 + cg_ * 8);
        of[0] = (float4){y[0], y[1], y[2], y[3]};
        of[1] = (float4){y[4], y[5], y[6], y[7]};
        bf16x8 o;
#pragma unroll
        for (int e = 0; e < 8; e++) o[e] = (bf16)y[e];
        *(bf16x8*)(p.X0h + grow * 128 + cg_ * 8) = o;
    }
}

// ---------------------------------------------------------------------------
// Wide MFMA GEMM body for cross Q/KV scatter modes.
__device__ __forceinline__ void gemm4_body(
    int bid, const bf16* __restrict__ A, const bf16* __restrict__ W,
    const float* __restrict__ bias, bf16* __restrict__ dq,
    bf16* __restrict__ dk, bf16* __restrict__ dvv, int N, int K, int mode) {
    int lane = threadIdx.x & 63;
    int wv = threadIdx.x >> 6;
    int c = lane & 15, g = lane >> 4;
    int nN = N >> 6;
    int tn = bid % nN, tm = bid / nN;
    int row0 = tm * 64 + wv * 16;
    int cb = tn * 64;

    const bf16x8* Ap  = (const bf16x8*)(A + (size_t)(row0 + c) * K) + g;
    const bf16x8* Wp0 = (const bf16x8*)(W + (size_t)(cb + c) * K) + g;
    const bf16x8* Wp1 = (const bf16x8*)(W + (size_t)(cb + 16 + c) * K) + g;
    const bf16x8* Wp2 = (const bf16x8*)(W + (size_t)(cb + 32 + c) * K) + g;
    const bf16x8* Wp3 = (const bf16x8*)(W + (size_t)(cb + 48 + c) * K) + g;
    f32x4 a0 = {0, 0, 0, 0}, a1 = {0, 0, 0, 0};
    f32x4 a2 = {0, 0, 0, 0}, a3 = {0, 0, 0, 0};
    int nk = K >> 5;
    for (int k = 0; k < nk; k++) {
        bf16x8 av = Ap[k * 4];
        a0 = __builtin_amdgcn_mfma_f32_16x16x32_bf16(av, Wp0[k * 4], a0, 0, 0, 0);
        a1 = __builtin_amdgcn_mfma_f32_16x16x32_bf16(av, Wp1[k * 4], a1, 0, 0, 0);
        a2 = __builtin_amdgcn_mfma_f32_16x16x32_bf16(av, Wp2[k * 4], a2, 0, 0, 0);
        a3 = __builtin_amdgcn_mfma_f32_16x16x32_bf16(av, Wp3[k * 4], a3, 0, 0, 0);
    }
    int rowb = row0 + g * 4;
#pragma unroll
    for (int ct = 0; ct < 4; ct++) {
        f32x4 acc = (ct == 0) ? a0 : (ct == 1) ? a1 : (ct == 2) ? a2 : a3;
        int col = cb + ct * 16 + c;
        float bvv = bias[col];
#pragma unroll
        for (int i = 0; i < 4; i++) {
            float v = acc[i] + bvv;
            int row = rowb + i;
            if (mode == 2) {
                int b = row >> 11, ll = row & 2047;
                int hh = col >> 5, d = col & 31;
                dq[((size_t)(b * 4 + hh) * 2048 + ll) * 32 + d] = (bf16)v;
            } else {
                int b = row >> 11, n = (row >> 8) & 7, t = row & 255;
                int ll = t * 8 + n;
                int hh = (col >> 5) & 3, d = col & 31;
                if (col < 128) dk[((size_t)(b * 4 + hh) * 2048 + ll) * 32 + d] = (bf16)v;
                else           dvv[((size_t)(b * 4 + hh) * 32 + d) * 2048 + ll] = (bf16)v;
            }
        }
    }
}

__device__ __forceinline__ void ph_qkvc(const KParams& p) {
    for (int vb = blockIdx.x; vb < 768; vb += 512) {
        if (vb < 256)
            gemm4_body(vb, p.sembh, p.Wpk + 262144, p.cabq, p.Qh, nullptr, nullptr, 128, 128, 2);
        else
            gemm4_body(vb - 256, p.X0h, p.Wpk + 278528, p.bpk, nullptr, p.Kh, p.Vth, 256, 128, 3);
    }
}

// ---------------------------------------------------------------------------
// Cross attention: 64 q/wave, 4-way key-split, LDS combine.
__device__ __forceinline__ void ph_mattn(const KParams& p, SMem& sm) {
    const int Lq = 2048, Lk = 2048, NSH = 16;
    auto& O_lds = sm.ma.O;
    auto& L_lds = sm.ma.L;
    int sh = blockIdx.x % NSH;
    int qblk = blockIdx.x / NSH;
    int wv = threadIdx.x >> 6;
    int lane = threadIdx.x & 63;
    int c = lane & 15, g = lane >> 4;
    int q0 = qblk * 64;
    const f32x4 zero = {0, 0, 0, 0};

    bf16x8 bq[4];
#pragma unroll
    for (int qt = 0; qt < 4; qt++)
        bq[qt] = *(const bf16x8*)(
            p.Qh + ((size_t)sh * Lq + q0 + qt * 16 + c) * 32 + g * 8);

    int klen = Lk >> 2;
    int kbeg = wv * klen;
    const bf16* Kbase = p.Kh + (size_t)sh * Lk * 32 + (size_t)kbeg * 32;
    const bf16* Vbase = p.Vth + (size_t)sh * 32 * Lk + kbeg;

    f32x4 oT[4][2];
#pragma unroll
    for (int qt = 0; qt < 4; qt++) { oT[qt][0] = zero; oT[qt][1] = zero; }
    float lsum[4] = {0, 0, 0, 0};

    int ntiles = klen >> 5;
    bf16x8 ka = *(const bf16x8*)(Kbase + (size_t)c * 32 + g * 8);
    bf16x8 kb = *(const bf16x8*)(Kbase + (size_t)(16 + c) * 32 + g * 8);
    bf16x4 va0 = *(const bf16x4*)(Vbase + (size_t)c * Lk + g * 4);
    bf16x4 va1 = *(const bf16x4*)(Vbase + (size_t)c * Lk + 16 + g * 4);
    bf16x4 vb0 = *(const bf16x4*)(Vbase + (size_t)(16 + c) * Lk + g * 4);
    bf16x4 vb1 = *(const bf16x4*)(Vbase + (size_t)(16 + c) * Lk + 16 + g * 4);

    for (int t = 0; t < ntiles; t++) {
        bf16x8 cka = ka, ckb = kb;
        bf16x4 cva0 = va0, cva1 = va1, cvb0 = vb0, cvb1 = vb1;
        int nk0 = ((t + 1 < ntiles) ? (t + 1) : t) << 5;
        ka = *(const bf16x8*)(Kbase + (size_t)(nk0 + c) * 32 + g * 8);
        kb = *(const bf16x8*)(Kbase + (size_t)(nk0 + 16 + c) * 32 + g * 8);
        va0 = *(const bf16x4*)(Vbase + (size_t)c * Lk + nk0 + g * 4);
        va1 = *(const bf16x4*)(Vbase + (size_t)c * Lk + nk0 + 16 + g * 4);
        vb0 = *(const bf16x4*)(Vbase + (size_t)(16 + c) * Lk + nk0 + g * 4);
        vb1 = *(const bf16x4*)(Vbase + (size_t)(16 + c) * Lk + nk0 + 16 + g * 4);

#pragma unroll
        for (int qt = 0; qt < 4; qt++) {
            f32x4 s0 = __builtin_amdgcn_mfma_f32_16x16x32_bf16(cka, bq[qt], zero, 0, 0, 0);
            f32x4 s1 = __builtin_amdgcn_mfma_f32_16x16x32_bf16(ckb, bq[qt], zero, 0, 0, 0);
            bf16x4 p0, p1;
#pragma unroll
            for (int r = 0; r < 4; r++) {
                float e0 = exp2_fast(s0[r] * SCALE_LOG2E);
                float e1 = exp2_fast(s1[r] * SCALE_LOG2E);
                lsum[qt] += e0 + e1;
                p0[r] = (bf16)e0;
                p1[r] = (bf16)e1;
            }
            oT[qt][0] = pv_mfma16(cva0, p0, oT[qt][0]);
            oT[qt][0] = pv_mfma16(cva1, p1, oT[qt][0]);
            oT[qt][1] = pv_mfma16(cvb0, p0, oT[qt][1]);
            oT[qt][1] = pv_mfma16(cvb1, p1, oT[qt][1]);
        }
    }

#pragma unroll
    for (int qt = 0; qt < 4; qt++) {
        float s = lsum[qt];
        s += __shfl_xor(s, 16);
        s += __shfl_xor(s, 32);
        if (g == 0) L_lds[wv][qt * 16 + c] = s;
        *(f32x4*)&O_lds[wv][qt * 16 + c][g * 4] = oT[qt][0];
        *(f32x4*)&O_lds[wv][qt * 16 + c][16 + g * 4] = oT[qt][1];
    }
    __syncthreads();

    int tid = threadIdx.x;
    int ql = tid >> 2, dq = (tid & 3) * 8;
    float ltot = L_lds[0][ql] + L_lds[1][ql] + L_lds[2][ql] + L_lds[3][ql];
    float inv = 1.0f / ltot;
    float acc[8];
#pragma unroll
    for (int j = 0; j < 8; j++) acc[j] = 0.0f;
#pragma unroll
    for (int w = 0; w < 4; w++) {
        const float* pp = &O_lds[w][ql][dq];
#pragma unroll
        for (int j = 0; j < 8; j++) acc[j] += pp[j];
    }
    int h = sh & 3, sb = sh >> 2;
    bf16x8 o;
#pragma unroll
    for (int j = 0; j < 8; j++) o[j] = (bf16)(acc[j] * inv);
    *(bf16x8*)(p.ATTh + ((size_t)sb * Lq + q0 + ql) * 128 + h * 32 + dq) = o;
}

// ---------------------------------------------------------------------------
// Cross tail.
__device__ __forceinline__ void ph_ctail(const KParams& p, SMem& sm) {
    const bf16* Wo = p.Wpk + 311296;
    const bf16* W1 = p.Wpk + 327680;
    const bf16* W2 = p.Wpk + 458752;
    auto& S = sm.ctail.S;
    auto& s1h = sm.ctail.s1h;
    auto& H = sm.ctail.H;
    int tid = threadIdx.x;
    int w = tid >> 6, lane = tid & 63;
    int c = lane & 15, gq = lane >> 4;
    int blk = blockIdx.x;
    const f32x4 zero = {0, 0, 0, 0};

    bf16x8 agl[4];
    {
        int tr = blk * 16 + c;
        int b = tr >> 11, t = (tr >> 3) & 255, n = tr & 7;
        const bf16* xrow = p.X0h + ((size_t)((b * 8 + n) * 256 + t)) * 128;
#pragma unroll
        for (int k = 0; k < 4; k++)
            agl[k] = *(const bf16x8*)(xrow + k * 32 + gq * 8);
    }

    {
        int cb = w * 32;
        const bf16x8* Ap  = (const bf16x8*)(p.ATTh + (size_t)(blk * 16 + c) * 128) + gq;
        const bf16x8* Wp0 = (const bf16x8*)(Wo + (size_t)(cb + c) * 128) + gq;
        const bf16x8* Wp1 = (const bf16x8*)(Wo + (size_t)(cb + 16 + c) * 128) + gq;
        f32x4 a0 = zero, a1 = zero;
#pragma unroll
        for (int k = 0; k < 4; k++) {
            bf16x8 av = Ap[k * 4];
            a0 = __builtin_amdgcn_mfma_f32_16x16x32_bf16(av, Wp0[k * 4], a0, 0, 0, 0);
            a1 = __builtin_amdgcn_mfma_f32_16x16x32_bf16(av, Wp1[k * 4], a1, 0, 0, 0);
        }
#pragma unroll
        for (int r = 0; r < 4; r++) {
            S[gq * 4 + r][cb + c] = a0[r] + p.cabo[cb + c];
            S[gq * 4 + r][cb + 16 + c] = a1[r] + p.cabo[cb + 16 + c];
        }
    }
    __syncthreads();
    {
        int row = tid >> 4, cg_ = tid & 15;
        float v[8];
        const float4* rp = (const float4*)(p.semb + (size_t)(blk * 16 + row) * 128 + cg_ * 8);
        float4 r0 = rp[0], r1 = rp[1];
        v[0] = S[row][cg_ * 8 + 0] + r0.x; v[1] = S[row][cg_ * 8 + 1] + r0.y;
        v[2] = S[row][cg_ * 8 + 2] + r0.z; v[3] = S[row][cg_ * 8 + 3] + r0.w;
        v[4] = S[row][cg_ * 8 + 4] + r1.x; v[5] = S[row][cg_ * 8 + 5] + r1.y;
        v[6] = S[row][cg_ * 8 + 6] + r1.z; v[7] = S[row][cg_ * 8 + 7] + r1.w;
        float s = 0.0f;
#pragma unroll
        for (int j = 0; j < 8; j++) s += v[j];
        s += __shfl_xor(s, 1); s += __shfl_xor(s, 2);
        s += __shfl_xor(s, 4); s += __shfl_xor(s, 8);
        float mean = s * (1.0f / 128.0f);
        float vs = 0.0f;
#pragma unroll
        for (int j = 0; j < 8; j++) { float d = v[j] - mean; vs += d * d; }
        vs += __shfl_xor(vs, 1); vs += __shfl_xor(vs, 2);
        vs += __shfl_xor(vs, 4); vs += __shfl_xor(vs, 8);
        float rstd = rsqrtf(vs * (1.0f / 128.0f) + 1e-5f);
#pragma unroll
        for (int j = 0; j < 8; j++) {
            int col = cg_ * 8 + j;
            s1h[row][col] = (bf16)((v[j] - mean) * rstd * p.cln1g[col] + p.cln1b[col]);
        }
    }
    __syncthreads();
    {
        bf16x8 afl[4];
#pragma unroll
        for (int k = 0; k < 4; k++)
            afl[k] = *(const bf16x8*)&s1h[c][k * 32 + gq * 8];
#pragma unroll
        for (int ci = 0; ci < 2; ci++) {
            int cb2 = w * 128 + ci * 64;
            const bf16x8* Wp0 = (const bf16x8*)(W1 + (size_t)(cb2 + c) * 256) + gq;
            const bf16x8* Wp1 = (const bf16x8*)(W1 + (size_t)(cb2 + 16 + c) * 256) + gq;
            const bf16x8* Wp2 = (const bf16x8*)(W1 + (size_t)(cb2 + 32 + c) * 256) + gq;
            const bf16x8* Wp3 = (const bf16x8*)(W1 + (size_t)(cb2 + 48 + c) * 256) + gq;
            f32x4 a0 = zero, a1 = zero, a2 = zero, a3 = zero;
#pragma unroll
            for (int k = 0; k < 8; k++) {
                bf16x8 av = (k < 4) ? afl[k] : agl[k - 4];
                a0 = __builtin_amdgcn_mfma_f32_16x16x32_bf16(av, Wp0[k * 4], a0, 0, 0, 0);
                a1 = __builtin_amdgcn_mfma_f32_16x16x32_bf16(av, Wp1[k * 4], a1, 0, 0, 0);
                a2 = __builtin_amdgcn_mfma_f32_16x16x32_bf16(av, Wp2[k * 4], a2, 0, 0, 0);
                a3 = __builtin_amdgcn_mfma_f32_16x16x32_bf16(av, Wp3[k * 4], a3, 0, 0, 0);
            }
#pragma unroll
            for (int r = 0; r < 4; r++) {
                H[gq * 4 + r][cb2 + c]      = (bf16)gelu_f(a0[r] + p.cffb1[cb2 + c]);
                H[gq * 4 + r][cb2 + 16 + c] = (bf16)gelu_f(a1[r] + p.cffb1[cb2 + 16 + c]);
                H[gq * 4 + r][cb2 + 32 + c] = (bf16)gelu_f(a2[r] + p.cffb1[cb2 + 32 + c]);
                H[gq * 4 + r][cb2 + 48 + c] = (bf16)gelu_f(a3[r] + p.cffb1[cb2 + 48 + c]);
            }
        }
    }
    __syncthreads();
    {
        int cb = w * 32;
        const bf16x8* Wp0 = (const bf16x8*)(W2 + (size_t)(cb + c) * 512) + gq;
        const bf16x8* Wp1 = (const bf16x8*)(W2 + (size_t)(cb + 16 + c) * 512) + gq;
        f32x4 a0 = zero, a1 = zero;
#pragma unroll
        for (int k = 0; k < 16; k++) {
            bf16x8 av = *(const bf16x8*)&H[c][k * 32 + gq * 8];
            a0 = __builtin_amdgcn_mfma_f32_16x16x32_bf16(av, Wp0[k * 4], a0, 0, 0, 0);
            a1 = __builtin_amdgcn_mfma_f32_16x16x32_bf16(av, Wp1[k * 4], a1, 0, 0, 0);
        }
#pragma unroll
        for (int r = 0; r < 4; r++) {
            S[gq * 4 + r][cb + c] = a0[r] + p.cffb2[cb + c];
            S[gq * 4 + r][cb + 16 + c] = a1[r] + p.cffb2[cb + 16 + c];
        }
    }
    __syncthreads();
    {
        int row = tid >> 4, cg_ = tid & 15;
        float v[8];
#pragma unroll
        for (int j = 0; j < 8; j++)
            v[j] = S[row][cg_ * 8 + j] + (float)s1h[row][cg_ * 8 + j];
        float s = 0.0f;
#pragma unroll
        for (int j = 0; j < 8; j++) s += v[j];
        s += __shfl_xor(s, 1); s += __shfl_xor(s, 2);
        s += __shfl_xor(s, 4); s += __shfl_xor(s, 8);
        float mean = s * (1.0f / 128.0f);
        float vs = 0.0f;
#pragma unroll
        for (int j = 0; j < 8; j++) { float d = v[j] - mean; vs += d * d; }
        vs += __shfl_xor(vs, 1); vs += __shfl_xor(vs, 2);
        vs += __shfl_xor(vs, 4); vs += __shfl_xor(vs, 8);
        float rstd = rsqrtf(vs * (1.0f / 128.0f) + 1e-5f);
        float y[8];
#pragma unroll
        for (int j = 0; j < 8; j++) {
            int col = cg_ * 8 + j;
            y[j] = (v[j] - mean) * rstd * p.cln2g[col] + p.cln2b[col];
        }
        float4* of = (float4*)(p.out + (size_t)(blk * 16 + row) * 128 + cg_ * 8);
        of[0] = (float4){y[0], y[1], y[2], y[3]};
        of[1] = (float4){y[4], y[5], y[6], y[7]};
    }
}

// ---------------------------------------------------------------------------
// Fused cooperative kernel: whole forward pass, 8 grid syncs, 1 dispatch.
__global__ __launch_bounds__(256, 2) void k_fused(KParams p, const float* mlpW2src) {
    cg::grid_group grid = cg::this_grid();
    __shared__ SMem sm;

    ph_prep(p);
    ph_prep_mlpw2(p, mlpW2src);
    grid.sync();
    ph_mlp(p, sm);
    grid.sync();
    for (int i = 0; i < LENC_; i++) {
        ph_attn(p, sm, i);
        grid.sync();
        ph_etail(p, sm, i);
        grid.sync();
    }
    ph_qkvc(p);
    grid.sync();
    ph_mattn(p, sm);
    grid.sync();
    ph_ctail(p, sm);
}

// ===========================================================================
// Legacy 8-dispatch path (fallback if cooperative launch fails).
// ===========================================================================
__global__ void k_prep_b1(const float* __restrict__ eqkvW, const float* __restrict__ eoutW,
                          const float* __restrict__ eff1, const float* __restrict__ eff2,
                          const float* __restrict__ wq, const float* __restrict__ wk,
                          const float* __restrict__ wv, const float* __restrict__ wo,
                          const float* __restrict__ cff1, const float* __restrict__ cff2,
                          const float* __restrict__ mlpW2, const float* __restrict__ semb,
                          const float* __restrict__ bk, const float* __restrict__ bv,
                          bf16* __restrict__ Wpk, bf16* __restrict__ sembh,
                          float* __restrict__ bpk,
                          const float* __restrict__ vs, const float* __restrict__ r5,
                          const float* __restrict__ A55, const float* __restrict__ bl_bias,
                          const float* __restrict__ nlW1, const float* __restrict__ nlb1,
                          const float* __restrict__ nlW2, const float* __restrict__ nlb2,
                          float* __restrict__ b1w) {
    if (blockIdx.x < 6209) {
        int i = blockIdx.x * 256 + threadIdx.x;
        if (i < 540672) {
            const float* src; int off;
            if      (i < 98304)  { src = eqkvW; off = 0; }
            else if (i < 131072) { src = eoutW; off = 98304; }
            else if (i < 196608) { src = eff1;  off = 131072; }
            else if (i < 262144) { src = eff2;  off = 196608; }
            else if (i < 278528) { src = wq;    off = 262144; }
            else if (i < 294912) { src = wk;    off = 278528; }
            else if (i < 311296) { src = wv;    off = 294912; }
            else if (i < 327680) { src = wo;    off = 311296; }
            else if (i < 458752) { src = cff1;  off = 327680; }
            else if (i < 524288) { src = cff2;  off = 458752; }
            else                 { src = mlpW2; off = 524288; }
            Wpk[i] = (bf16)src[i - off];
        } else if (i < 540672 + 1048576) {
            int j = i - 540672;
            sembh[j] = (bf16)semb[j];
        } else if (i < 540672 + 1048576 + 256) {
            int t = i - 540672 - 1048576;
            bpk[t] = (t < 128) ? bk[t] : bv[t - 128];
        }
        return;
    }
    int idx = (blockIdx.x - 6209) * 256 + threadIdx.x;
    if (idx >= B_ * (T_ - 1)) return;
    int b = idx / (T_ - 1), t = idx % (T_ - 1);
    float x[N_];
    for (int n = 0; n < N_; n++) x[n] = vs[(b * T_ + t) * N_ + n];
    float h[MLPH_];
    for (int j = 0; j < MLPH_; j++) {
        float a = nlb1[j];
        for (int n = 0; n < N_; n++) a += x[n] * nlW1[j * N_ + n];
        h[j] = gelu_f(a);
    }
    for (int m = 0; m < N_; m++) {
        float lin = r5[m];
        for (int n = 0; n < N_; n++) lin += x[n] * A55[m * N_ + n];
        float nl = nlb2[m];
        for (int j = 0; j < MLPH_; j++) nl += h[j] * nlW2[m * MLPH_ + j];
        b1w[idx * N_ + m] = lin + NL_SCALE_ * nl + bl_bias[m];
    }
}

__global__ __launch_bounds__(256) void k_mlp_ln_leg(KParams p) {
    __shared__ SMem sm;
    ph_mlp(p, sm);
}
__global__ __launch_bounds__(256) void k_enc_attn_leg(KParams p, int layer) {
    __shared__ SMem sm;
    ph_attn(p, sm, layer);
}
__global__ __launch_bounds__(256) void k_enc_tail_leg(KParams p, int layer) {
    __shared__ SMem sm;
    ph_etail(p, sm, layer);
}
__global__ __launch_bounds__(256) void k_qkvc_leg(KParams p) {
    if (blockIdx.x < 256)
        gemm4_body(blockIdx.x, p.sembh, p.Wpk + 262144, p.cabq, p.Qh, nullptr, nullptr, 128, 128, 2);
    else
        gemm4_body(blockIdx.x - 256, p.X0h, p.Wpk + 278528, p.bpk, nullptr, p.Kh, p.Vth, 256, 128, 3);
}
__global__ __launch_bounds__(256) void k_mattn_leg(KParams p) {
    __shared__ SMem sm;
    ph_mattn(p, sm);
}
__global__ __launch_bounds__(256) void k_ctail_leg(KParams p) {
    __shared__ SMem sm;
    ph_ctail(p, sm);
}

// ---------------------------------------------------------------------------
extern "C" void kernel_launch(void* const* d_in, const int* in_sizes, int n_in,
                              void* d_out, int out_size, void* d_ws, size_t ws_size,
                              hipStream_t stream) {
    KParams p;
    p.vs      = (const float*)d_in[0];
    p.semb    = (const float*)d_in[1];
    p.r5      = (const float*)d_in[2];
    p.A55     = (const float*)d_in[3];
    p.bl_bias = (const float*)d_in[4];
    p.nlW1    = (const float*)d_in[5];
    p.nlb1    = (const float*)d_in[6];
    p.nlW2    = (const float*)d_in[7];
    p.nlb2    = (const float*)d_in[8];
    p.mlpW1   = (const float*)d_in[9];
    p.mlpb1   = (const float*)d_in[10];
    const float* mlpW2 = (const float*)d_in[11];
    p.mlpb2   = (const float*)d_in[12];
    p.mlplng  = (const float*)d_in[13];
    p.mlplnb  = (const float*)d_in[14];
    p.eqkvW   = (const float*)d_in[15];
    p.eqkvb   = (const float*)d_in[16];
    p.eoutW   = (const float*)d_in[17];
    p.eoutb   = (const float*)d_in[18];
    p.eln1g   = (const float*)d_in[19];
    p.eln1b   = (const float*)d_in[20];
    p.eff1    = (const float*)d_in[21];
    p.effb1   = (const float*)d_in[22];
    p.eff2    = (const float*)d_in[23];
    p.effb2   = (const float*)d_in[24];
    p.eln2g   = (const float*)d_in[25];
    p.eln2b   = (const float*)d_in[26];
    p.caWq = (const float*)d_in[27];
    p.cabq = (const float*)d_in[28];
    p.caWk = (const float*)d_in[29];
    p.cabk = (const float*)d_in[30];
    p.caWv = (const float*)d_in[31];
    p.cabv = (const float*)d_in[32];
    p.caWo = (const float*)d_in[33];
    p.cabo = (const float*)d_in[34];
    p.cln1g = (const float*)d_in[35];
    p.cln1b = (const float*)d_in[36];
    p.cff1  = (const float*)d_in[37];
    p.cffb1 = (const float*)d_in[38];
    p.cff2  = (const float*)d_in[39];
    p.cffb2 = (const float*)d_in[40];
    p.cln2g = (const float*)d_in[41];
    p.cln2b = (const float*)d_in[42];
    p.out = (float*)d_out;

    char* base = (char*)d_ws;
    p.b1w   = (float*)(base + 0);
    p.X0    = (float*)(base + 163840);
    char* QKVr = base + 8552448;
    p.Wpk   = (bf16*) (base + 25329664);
    p.bpk   = (float*)(base + 26411008);
    p.X0h   = (bf16*) (base + 26412032);
    p.sembh = (bf16*) (base + 30606336);
    p.ATTh  = (bf16*) (base + 32703488);
    p.Qh    = (bf16*)QKVr;
    p.Kh    = (bf16*)(QKVr + 2097152);
    p.Vth   = (bf16*)(QKVr + 4194304);

    // Single fused cooperative dispatch (8 launches -> 1).
    void* kargs[2] = { &p, &mlpW2 };
    hipError_t err = hipLaunchCooperativeKernel(
        (const void*)k_fused, dim3(512), dim3(256), kargs, 0, stream);
    if (err == hipSuccess) return;

    // Fallback: legacy 8-dispatch sequence.
    k_prep_b1<<<dim3(6213), dim3(256), 0, stream>>>(
        p.eqkvW, p.eoutW, p.eff1, p.eff2, p.caWq, p.caWk, p.caWv, p.caWo,
        p.cff1, p.cff2, mlpW2, p.semb, p.cabk, p.cabv, p.Wpk, p.sembh, p.bpk,
        p.vs, p.r5, p.A55, p.bl_bias, p.nlW1, p.nlb1, p.nlW2, p.nlb2, p.b1w);
    k_mlp_ln_leg<<<dim3(512), dim3(256), 0, stream>>>(p);
    for (int i = 0; i < LENC_; i++) {
        k_enc_attn_leg<<<dim3(512), dim3(256), 0, stream>>>(p, i);
        k_enc_tail_leg<<<dim3(512), dim3(256), 0, stream>>>(p, i);
    }
    k_qkvc_leg<<<dim3(768), dim3(256), 0, stream>>>(p);
    k_mattn_leg<<<dim3(512), dim3(256), 0, stream>>>(p);
    k_ctail_leg<<<dim3(512), dim3(256), 0, stream>>>(p);
}

// Round 4
// 313.645 us; speedup vs baseline: 2.6627x; 2.6627x over previous
//
#include <hip/hip_runtime.h>
#include <math.h>

// Problem constants
#define B_ 4
#define T_ 256
#define N_ 8
#define D_ 128
#define NH_ 4
#define HD_ 32
#define LENC_ 2
#define MLPH_ 32
#define NL_SCALE_ 0.1f

typedef __bf16 bf16;
typedef __attribute__((ext_vector_type(2))) __bf16 bf16x2;
typedef __attribute__((ext_vector_type(4))) __bf16 bf16x4;
typedef __attribute__((ext_vector_type(8))) __bf16 bf16x8;
typedef __attribute__((ext_vector_type(4))) float f32x4;

__device__ __forceinline__ f32x4 pv_mfma16(bf16x4 a, bf16x4 b, f32x4 c) {
#if __has_builtin(__builtin_amdgcn_mfma_f32_16x16x16_bf16)
    return __builtin_amdgcn_mfma_f32_16x16x16_bf16(a, b, c, 0, 0, 0);
#else
    typedef __attribute__((ext_vector_type(4))) short s4;
    union U { bf16x4 h; s4 s; };
    U ua, ub; ua.h = a; ub.h = b;
    return __builtin_amdgcn_mfma_f32_16x16x16bf16_1k(ua.s, ub.s, c, 0, 0, 0);
#endif
}

__device__ __forceinline__ float gelu_f(float x) {
    return 0.5f * x * (1.0f + erff(x * 0.7071067811865476f));
}

// 2^x directly on the trans pipe.
__device__ __forceinline__ float exp2_fast(float x) {
#if __has_builtin(__builtin_amdgcn_exp2f)
    return __builtin_amdgcn_exp2f(x);
#else
    return __expf(x * 0.6931471805599453f);
#endif
}

// log2(e) / sqrt(32) — folded into Q at projection time; attention uses exp2(s).
#define SCALE_LOG2E 0.25503486f

// ---------------------------------------------------------------------------
// Fused: weight pack (grid-stride) + per-block b1 baseline (LDS) + features
// + mlp1 + inline-converted W2 GEMM + gelu + LN + PE + transpose write.
// 16 rows/block, grid = 512. Replaces the old prep dispatch entirely.
__global__ __launch_bounds__(256) void k_mlp_prep(
    const float* __restrict__ vs,
    const float* __restrict__ mlpW1, const float* __restrict__ mlpb1,
    const float* __restrict__ mlpW2f, const float* __restrict__ mlpb2,
    const float* __restrict__ lng, const float* __restrict__ lnb,
    const float* __restrict__ r5, const float* __restrict__ A55,
    const float* __restrict__ bl_bias,
    const float* __restrict__ nlW1, const float* __restrict__ nlb1,
    const float* __restrict__ nlW2, const float* __restrict__ nlb2,
    const float* __restrict__ eqkvW, const float* __restrict__ eoutW,
    const float* __restrict__ eff1, const float* __restrict__ eff2,
    const float* __restrict__ caWq, const float* __restrict__ caWk,
    const float* __restrict__ caWv, const float* __restrict__ caWo,
    const float* __restrict__ cff1, const float* __restrict__ cff2,
    const float* __restrict__ semb, const float* __restrict__ cabk,
    const float* __restrict__ cabv,
    bf16* __restrict__ Wpk, bf16* __restrict__ sembh, float* __restrict__ bpk,
    float* __restrict__ X0, bf16* __restrict__ X0h) {
    __shared__ float F[16][16];
    __shared__ float b1loc[9][8];
    __shared__ bf16 H1[16][136];
    __shared__ float S[16][132];
    int tid = threadIdx.x;
    int blk = blockIdx.x;

    // Phase A: weight pack + sembh + bpk, grid-strided (consumed by LATER
    // dispatches only — stream order guarantees visibility).
    {
        const int NPK = 524288, NSB = 1048576;
        for (int it = blk * 256 + tid; it < NPK + NSB + 256; it += 512 * 256) {
            if (it < NPK) {
                int i = it;
                const float* src; int off;
                if      (i < 98304)  { src = eqkvW; off = 0; }
                else if (i < 131072) { src = eoutW; off = 98304; }
                else if (i < 196608) { src = eff1;  off = 131072; }
                else if (i < 262144) { src = eff2;  off = 196608; }
                else if (i < 278528) { src = caWq;  off = 262144; }
                else if (i < 294912) { src = caWk;  off = 278528; }
                else if (i < 311296) { src = caWv;  off = 294912; }
                else if (i < 327680) { src = caWo;  off = 311296; }
                else if (i < 458752) { src = cff1;  off = 327680; }
                else                 { src = cff2;  off = 458752; }
                Wpk[i] = (bf16)src[i - off];
            } else if (it < NPK + NSB) {
                int j = it - NPK;
                sembh[j] = (bf16)semb[j];
            } else {
                int t = it - NPK - NSB;
                bpk[t] = (t < 128) ? cabk[t] : cabv[t - 128];
            }
        }
    }

    // Phase B: b1 baseline for this block's t-window into LDS.
    // Block covers rows grow = blk*16..+15 -> b = blk>>7, t in {t0, t0+1}.
    // Features need b1[t'] for t' in [t0-3, t0+5] (9 values) x 8 n.
    int t0 = (blk * 2) & 255;
    int bB = blk >> 7;
    if (tid < 72) {
        int tt = t0 - 3 + (tid >> 3);
        int m = tid & 7;
        if (tt >= 0 && tt < T_ - 1) {
            float x[N_];
#pragma unroll
            for (int n = 0; n < N_; n++) x[n] = vs[(bB * T_ + tt) * N_ + n];
            float h[MLPH_];
#pragma unroll
            for (int j = 0; j < MLPH_; j++) {
                float a = nlb1[j];
#pragma unroll
                for (int n = 0; n < N_; n++) a += x[n] * nlW1[j * N_ + n];
                h[j] = gelu_f(a);
            }
            float lin = r5[m];
#pragma unroll
            for (int n = 0; n < N_; n++) lin += x[n] * A55[m * N_ + n];
            float nl = nlb2[m];
#pragma unroll
            for (int j = 0; j < MLPH_; j++) nl += h[j] * nlW2[m * MLPH_ + j];
            b1loc[tid >> 3][m] = lin + NL_SCALE_ * nl + bl_bias[m];
        }
    }
    __syncthreads();

    // Phase C: one feature per thread (16 rows x 16 feats), b1 from LDS.
    {
        int row = tid >> 4, feat = tid & 15;
        int t = t0 + (row >> 3), n = row & 7;
        const int SC[4] = {1, 2, 3, 5};
        int lag = feat >> 2, si = feat & 3, k = SC[si];
        int tp = t - lag;
        float r = 0.0f;
        if (tp >= 0 && tp < T_ - k) {
            float lx0 = logf(fmaxf(vs[(bB * T_ + tp) * N_ + n], 1e-6f));
            float lx1 = logf(fmaxf(vs[(bB * T_ + tp + k) * N_ + n], 1e-6f));
            float a = lx1 - lx0;
            a = fminf(fmaxf(a, -2.5f * (float)k), 2.0f * (float)k);
            float bk = 0.0f;
            for (int i = 0; i < k; i++) bk += b1loc[tp + i - t0 + 3][n];
            r = a - bk;
        }
        F[row][feat] = r;
    }
    __syncthreads();
    // Phase D: H1[row][d] = gelu(b1[d] + F[row] . W1[d]); 8 cols/thread
    {
        int row = tid >> 4, cg_ = tid & 15;
        float f[16];
#pragma unroll
        for (int c = 0; c < 16; c++) f[c] = F[row][c];
#pragma unroll
        for (int j = 0; j < 8; j++) {
            int d = cg_ * 8 + j;
            float a = mlpb1[d];
            const float* w = mlpW1 + d * 16;
#pragma unroll
            for (int c = 0; c < 16; c++) a += f[c] * w[c];
            H1[row][d] = (bf16)gelu_f(a);
        }
    }
    __syncthreads();
    // Phase E: GEMM (K=128, N=128); W2 loaded fp32 and converted inline
    // (bitwise identical to the old pack-then-load path).
    int w = tid >> 6, lane = tid & 63;
    int c = lane & 15, gq = lane >> 4;
    int cb = w * 32;
    const f32x4 zero = {0, 0, 0, 0};
    {
        const float* w0 = mlpW2f + (size_t)(cb + c) * 128 + gq * 8;
        const float* w1 = mlpW2f + (size_t)(cb + 16 + c) * 128 + gq * 8;
        f32x4 a0 = zero, a1 = zero;
#pragma unroll
        for (int k = 0; k < 4; k++) {
            bf16x8 av = *(const bf16x8*)&H1[c][k * 32 + gq * 8];
            bf16x8 wb0, wb1;
#pragma unroll
            for (int j = 0; j < 8; j++) {
                wb0[j] = (bf16)w0[k * 32 + j];
                wb1[j] = (bf16)w1[k * 32 + j];
            }
            a0 = __builtin_amdgcn_mfma_f32_16x16x32_bf16(av, wb0, a0, 0, 0, 0);
            a1 = __builtin_amdgcn_mfma_f32_16x16x32_bf16(av, wb1, a1, 0, 0, 0);
        }
#pragma unroll
        for (int r = 0; r < 4; r++) {
            S[gq * 4 + r][cb + c]      = gelu_f(a0[r] + mlpb2[cb + c]);
            S[gq * 4 + r][cb + 16 + c] = gelu_f(a1[r] + mlpb2[cb + 16 + c]);
        }
    }
    __syncthreads();
    // Phase F: LN + PE, transpose write. 16 threads/row, 8 cols each.
    {
        int row = tid >> 4, cg_ = tid & 15;
        int grow = blk * 16 + row;
        int b = grow >> 11, t = (grow >> 3) & 255, n = grow & 7;
        int orow = (b * 8 + n) * 256 + t;
        float v[8];
#pragma unroll
        for (int j = 0; j < 8; j++) v[j] = S[row][cg_ * 8 + j];
        float s = 0.0f;
#pragma unroll
        for (int j = 0; j < 8; j++) s += v[j];
        s += __shfl_xor(s, 1); s += __shfl_xor(s, 2);
        s += __shfl_xor(s, 4); s += __shfl_xor(s, 8);
        float mean = s * (1.0f / 128.0f);
        float vs2 = 0.0f;
#pragma unroll
        for (int j = 0; j < 8; j++) { float d = v[j] - mean; vs2 += d * d; }
        vs2 += __shfl_xor(vs2, 1); vs2 += __shfl_xor(vs2, 2);
        vs2 += __shfl_xor(vs2, 4); vs2 += __shfl_xor(vs2, 8);
        float rstd = rsqrtf(vs2 * (1.0f / 128.0f) + 1e-5f);
        float y[8];
#pragma unroll
        for (int j = 0; j < 8; j++) {
            int col = cg_ * 8 + j;
            y[j] = (v[j] - mean) * rstd * lng[col] + lnb[col];
        }
#pragma unroll
        for (int jj = 0; jj < 4; jj++) {
            int j2 = cg_ * 4 + jj;
            float freq = expf((float)(2 * j2) * (-9.210340371976184f / 128.0f));
            float ang = (float)t * freq;
            y[2 * jj] += sinf(ang);
            y[2 * jj + 1] += cosf(ang);
        }
        float4* of = (float4*)(X0 + (size_t)orow * 128 + cg_ * 8);
        of[0] = (float4){y[0], y[1], y[2], y[3]};
        of[1] = (float4){y[4], y[5], y[6], y[7]};
        bf16x8 o;
#pragma unroll
        for (int e = 0; e < 8; e++) o[e] = (bf16)y[e];
        *(bf16x8*)(X0h + (size_t)orow * 128 + cg_ * 8) = o;
    }
}

// ---------------------------------------------------------------------------
// Fused encoder QKV + attention: block = (seq-head, query-quarter), grid 512.
// Q is pre-scaled by SCALE_LOG2E so the softmax inner loop is exp2(s) with no
// per-element multiply.
__global__ __launch_bounds__(256) void k_enc_attn(
    const bf16* __restrict__ X0h, const bf16* __restrict__ Wqkv,
    const float* __restrict__ bqkv, bf16* __restrict__ ATTh) {
    int sh = blockIdx.x & 127;
    int qh = blockIdx.x >> 7;       // query quarter 0..3
    int s = sh >> 2, h = sh & 3;
    __shared__ bf16 Ql[64][40];
    __shared__ bf16 Kl[256][40];
    __shared__ bf16 Vt[32][264];
    int tid = threadIdx.x;
    int wv = tid >> 6, lane = tid & 63;
    int c = lane & 15, g = lane >> 4;
    const f32x4 zero = {0, 0, 0, 0};

    const bf16* Wq0 = Wqkv + (size_t)(h * 32 + c) * 128;
    const bf16* Wq1 = Wqkv + (size_t)(h * 32 + 16 + c) * 128;
    const bf16* Wk0 = Wqkv + (size_t)(128 + h * 32 + c) * 128;
    const bf16* Wk1 = Wqkv + (size_t)(128 + h * 32 + 16 + c) * 128;
    const bf16* Wv0 = Wqkv + (size_t)(256 + h * 32 + c) * 128;
    const bf16* Wv1 = Wqkv + (size_t)(256 + h * 32 + 16 + c) * 128;
    float bq0 = bqkv[h * 32 + c], bq1 = bqkv[h * 32 + 16 + c];
    float bk0 = bqkv[128 + h * 32 + c], bk1 = bqkv[128 + h * 32 + 16 + c];
    float bv0 = bqkv[256 + h * 32 + c], bv1 = bqkv[256 + h * 32 + 16 + c];

    // Phase 1a: K+V for all 256 keys (wave wv: rows wv*64..+63)
#pragma unroll
    for (int rb = 0; rb < 4; rb++) {
        int row0 = wv * 64 + rb * 16;
        const bf16x8* Ap = (const bf16x8*)(X0h + (size_t)(s * 256 + row0 + c) * 128) + g;
        f32x4 ak0 = zero, ak1 = zero, av0 = zero, av1 = zero;
#pragma unroll
        for (int k = 0; k < 4; k++) {
            bf16x8 av = Ap[k * 4];
            ak0 = __builtin_amdgcn_mfma_f32_16x16x32_bf16(av, *((const bf16x8*)Wk0 + k * 4 + g), ak0, 0, 0, 0);
            ak1 = __builtin_amdgcn_mfma_f32_16x16x32_bf16(av, *((const bf16x8*)Wk1 + k * 4 + g), ak1, 0, 0, 0);
            av0 = __builtin_amdgcn_mfma_f32_16x16x32_bf16(av, *((const bf16x8*)Wv0 + k * 4 + g), av0, 0, 0, 0);
            av1 = __builtin_amdgcn_mfma_f32_16x16x32_bf16(av, *((const bf16x8*)Wv1 + k * 4 + g), av1, 0, 0, 0);
        }
        int lr = row0 + g * 4;
#pragma unroll
        for (int i = 0; i < 4; i++) {
            Kl[lr + i][c] = (bf16)(ak0[i] + bk0);
            Kl[lr + i][16 + c] = (bf16)(ak1[i] + bk1);
            Vt[c][lr + i] = (bf16)(av0[i] + bv0);
            Vt[16 + c][lr + i] = (bf16)(av1[i] + bv1);
        }
    }
    // Phase 1b: Q for this block's 64 queries (wave wv: rows wv*16..+15),
    // pre-scaled by SCALE_LOG2E.
    {
        int row0q = wv * 16;
        const bf16x8* Ap = (const bf16x8*)(
            X0h + (size_t)(s * 256 + qh * 64 + row0q + c) * 128) + g;
        f32x4 aq0 = zero, aq1 = zero;
#pragma unroll
        for (int k = 0; k < 4; k++) {
            bf16x8 av = Ap[k * 4];
            aq0 = __builtin_amdgcn_mfma_f32_16x16x32_bf16(av, *((const bf16x8*)Wq0 + k * 4 + g), aq0, 0, 0, 0);
            aq1 = __builtin_amdgcn_mfma_f32_16x16x32_bf16(av, *((const bf16x8*)Wq1 + k * 4 + g), aq1, 0, 0, 0);
        }
        int lr = row0q + g * 4;
#pragma unroll
        for (int i = 0; i < 4; i++) {
            Ql[lr + i][c] = (bf16)((aq0[i] + bq0) * SCALE_LOG2E);
            Ql[lr + i][16 + c] = (bf16)((aq1[i] + bq1) * SCALE_LOG2E);
        }
    }
    __syncthreads();

    // Phase 2: attention. Wave wv: 16 queries (1 q-tile), 8 k-tiles.
    int q0l = wv * 16;
    bf16x8 bqv = *(const bf16x8*)&Ql[q0l + c][g * 8];
    f32x4 oT0 = zero, oT1 = zero;
    float lsum = 0.0f;
#pragma unroll
    for (int t = 0; t < 8; t++) {
        int k0 = t * 32;
        bf16x8 ka = *(const bf16x8*)&Kl[k0 + c][g * 8];
        bf16x8 kb = *(const bf16x8*)&Kl[k0 + 16 + c][g * 8];
        bf16x4 va0 = *(const bf16x4*)&Vt[c][k0 + g * 4];
        bf16x4 va1 = *(const bf16x4*)&Vt[c][k0 + 16 + g * 4];
        bf16x4 vb0 = *(const bf16x4*)&Vt[16 + c][k0 + g * 4];
        bf16x4 vb1 = *(const bf16x4*)&Vt[16 + c][k0 + 16 + g * 4];
        f32x4 s0 = __builtin_amdgcn_mfma_f32_16x16x32_bf16(ka, bqv, zero, 0, 0, 0);
        f32x4 s1 = __builtin_amdgcn_mfma_f32_16x16x32_bf16(kb, bqv, zero, 0, 0, 0);
        bf16x4 p0, p1;
#pragma unroll
        for (int r = 0; r < 4; r++) {
            float e0 = exp2_fast(s0[r]);
            float e1 = exp2_fast(s1[r]);
            lsum += e0 + e1;
            p0[r] = (bf16)e0;
            p1[r] = (bf16)e1;
        }
        oT0 = pv_mfma16(va0, p0, oT0);
        oT0 = pv_mfma16(va1, p1, oT0);
        oT1 = pv_mfma16(vb0, p0, oT1);
        oT1 = pv_mfma16(vb1, p1, oT1);
    }
    {
        float sm = lsum;
        sm += __shfl_xor(sm, 16);
        sm += __shfl_xor(sm, 32);
        float inv = 1.0f / sm;
        size_t rbase = ((size_t)s * 256 + qh * 64 + q0l + c) * 128 + h * 32;
#pragma unroll
        for (int r = 0; r < 4; r++) {
            ATTh[rbase + g * 4 + r] = (bf16)(oT0[r] * inv);
            ATTh[rbase + 16 + g * 4 + r] = (bf16)(oT1[r] * inv);
        }
    }
}

// ---------------------------------------------------------------------------
// Wide MFMA GEMM body for cross Q/KV scatter modes. qs = post-scale (Q path).
__device__ __forceinline__ void gemm4_body(
    int bid, const bf16* __restrict__ A, const bf16* __restrict__ W,
    const float* __restrict__ bias, bf16* __restrict__ dq,
    bf16* __restrict__ dk, bf16* __restrict__ dvv, int N, int K, int mode,
    float qs) {
    int lane = threadIdx.x & 63;
    int wv = threadIdx.x >> 6;
    int c = lane & 15, g = lane >> 4;
    int nN = N >> 6;
    int tn = bid % nN, tm = bid / nN;
    int row0 = tm * 64 + wv * 16;
    int cb = tn * 64;

    const bf16x8* Ap  = (const bf16x8*)(A + (size_t)(row0 + c) * K) + g;
    const bf16x8* Wp0 = (const bf16x8*)(W + (size_t)(cb + c) * K) + g;
    const bf16x8* Wp1 = (const bf16x8*)(W + (size_t)(cb + 16 + c) * K) + g;
    const bf16x8* Wp2 = (const bf16x8*)(W + (size_t)(cb + 32 + c) * K) + g;
    const bf16x8* Wp3 = (const bf16x8*)(W + (size_t)(cb + 48 + c) * K) + g;
    f32x4 a0 = {0, 0, 0, 0}, a1 = {0, 0, 0, 0};
    f32x4 a2 = {0, 0, 0, 0}, a3 = {0, 0, 0, 0};
    int nk = K >> 5;
    for (int k = 0; k < nk; k++) {
        bf16x8 av = Ap[k * 4];
        a0 = __builtin_amdgcn_mfma_f32_16x16x32_bf16(av, Wp0[k * 4], a0, 0, 0, 0);
        a1 = __builtin_amdgcn_mfma_f32_16x16x32_bf16(av, Wp1[k * 4], a1, 0, 0, 0);
        a2 = __builtin_amdgcn_mfma_f32_16x16x32_bf16(av, Wp2[k * 4], a2, 0, 0, 0);
        a3 = __builtin_amdgcn_mfma_f32_16x16x32_bf16(av, Wp3[k * 4], a3, 0, 0, 0);
    }
    int rowb = row0 + g * 4;
#pragma unroll
    for (int ct = 0; ct < 4; ct++) {
        f32x4 acc = (ct == 0) ? a0 : (ct == 1) ? a1 : (ct == 2) ? a2 : a3;
        int col = cb + ct * 16 + c;
        float bvv = bias[col];
#pragma unroll
        for (int i = 0; i < 4; i++) {
            float v = acc[i] + bvv;
            int row = rowb + i;
            if (mode == 2) {
                v *= qs;
                int b = row >> 11, ll = row & 2047;
                int hh = col >> 5, d = col & 31;
                dq[((size_t)(b * 4 + hh) * 2048 + ll) * 32 + d] = (bf16)v;
            } else {
                int b = row >> 11, n = (row >> 8) & 7, t = row & 255;
                int ll = t * 8 + n;
                int hh = (col >> 5) & 3, d = col & 31;
                if (col < 128) dk[((size_t)(b * 4 + hh) * 2048 + ll) * 32 + d] = (bf16)v;
                else           dvv[((size_t)(b * 4 + hh) * 32 + d) * 2048 + ll] = (bf16)v;
            }
        }
    }
}

// ---------------------------------------------------------------------------
// Encoder tail: 16 rows/block. Layer-1 launch uses grid 768: blocks 512..767
// run the cross Q-projection (depends only on sembh) instead of the tail.
__global__ __launch_bounds__(256) void k_enc_tail(
    const bf16* __restrict__ ATTh, const bf16* __restrict__ Wo,
    const float* __restrict__ bo, const float* __restrict__ X0res,
    const float* __restrict__ g1, const float* __restrict__ be1,
    const bf16* __restrict__ W1, const float* __restrict__ bf1,
    const bf16* __restrict__ W2, const float* __restrict__ bf2,
    const float* __restrict__ g2, const float* __restrict__ be2,
    float* __restrict__ X0out, bf16* __restrict__ X0hout,
    const bf16* __restrict__ sembh, const bf16* __restrict__ Wq,
    const float* __restrict__ bq, bf16* __restrict__ Qh) {
    if (blockIdx.x >= 512) {
        gemm4_body(blockIdx.x - 512, sembh, Wq, bq, Qh, nullptr, nullptr,
                   128, 128, 2, SCALE_LOG2E);
        return;
    }
    __shared__ float S[16][132];
    __shared__ float X1f[16][132];
    __shared__ bf16 X1h[16][136];
    __shared__ bf16 H[16][264];
    int tid = threadIdx.x;
    int w = tid >> 6, lane = tid & 63;
    int c = lane & 15, gq = lane >> 4;
    int blk = blockIdx.x;
    const f32x4 zero = {0, 0, 0, 0};

    // Phase 1: outproj (K=128, N=128). Wave wv cols w*32 (2 tiles).
    {
        int cb = w * 32;
        const bf16x8* Ap  = (const bf16x8*)(ATTh + (size_t)(blk * 16 + c) * 128) + gq;
        const bf16x8* Wp0 = (const bf16x8*)(Wo + (size_t)(cb + c) * 128) + gq;
        const bf16x8* Wp1 = (const bf16x8*)(Wo + (size_t)(cb + 16 + c) * 128) + gq;
        f32x4 a0 = zero, a1 = zero;
#pragma unroll
        for (int k = 0; k < 4; k++) {
            bf16x8 av = Ap[k * 4];
            a0 = __builtin_amdgcn_mfma_f32_16x16x32_bf16(av, Wp0[k * 4], a0, 0, 0, 0);
            a1 = __builtin_amdgcn_mfma_f32_16x16x32_bf16(av, Wp1[k * 4], a1, 0, 0, 0);
        }
#pragma unroll
        for (int r = 0; r < 4; r++) {
            S[gq * 4 + r][cb + c] = a0[r] + bo[cb + c];
            S[gq * 4 + r][cb + 16 + c] = a1[r] + bo[cb + 16 + c];
        }
    }
    __syncthreads();
    // Epilogue 1: + X0 residual, LN1 -> X1f + X1h
    {
        int row = tid >> 4, cg_ = tid & 15;
        float v[8];
        const float4* rp = (const float4*)(X0res + (size_t)(blk * 16 + row) * 128 + cg_ * 8);
        float4 r0 = rp[0], r1 = rp[1];
        v[0] = S[row][cg_ * 8 + 0] + r0.x; v[1] = S[row][cg_ * 8 + 1] + r0.y;
        v[2] = S[row][cg_ * 8 + 2] + r0.z; v[3] = S[row][cg_ * 8 + 3] + r0.w;
        v[4] = S[row][cg_ * 8 + 4] + r1.x; v[5] = S[row][cg_ * 8 + 5] + r1.y;
        v[6] = S[row][cg_ * 8 + 6] + r1.z; v[7] = S[row][cg_ * 8 + 7] + r1.w;
        float s = 0.0f;
#pragma unroll
        for (int j = 0; j < 8; j++) s += v[j];
        s += __shfl_xor(s, 1); s += __shfl_xor(s, 2);
        s += __shfl_xor(s, 4); s += __shfl_xor(s, 8);
        float mean = s * (1.0f / 128.0f);
        float vs = 0.0f;
#pragma unroll
        for (int j = 0; j < 8; j++) { float d = v[j] - mean; vs += d * d; }
        vs += __shfl_xor(vs, 1); vs += __shfl_xor(vs, 2);
        vs += __shfl_xor(vs, 4); vs += __shfl_xor(vs, 8);
        float rstd = rsqrtf(vs * (1.0f / 128.0f) + 1e-5f);
#pragma unroll
        for (int j = 0; j < 8; j++) {
            int col = cg_ * 8 + j;
            float y = (v[j] - mean) * rstd * g1[col] + be1[col];
            X1f[row][col] = y;
            X1h[row][col] = (bf16)y;
        }
    }
    __syncthreads();
    // Phase 2: ff1 (K=128, N=256). Wave wv cols w*64 (4 tiles).
    {
        int cb2 = w * 64;
        bf16x8 af[4];
#pragma unroll
        for (int k = 0; k < 4; k++)
            af[k] = *(const bf16x8*)&X1h[c][k * 32 + gq * 8];
        const bf16x8* Wp0 = (const bf16x8*)(W1 + (size_t)(cb2 + c) * 128) + gq;
        const bf16x8* Wp1 = (const bf16x8*)(W1 + (size_t)(cb2 + 16 + c) * 128) + gq;
        const bf16x8* Wp2 = (const bf16x8*)(W1 + (size_t)(cb2 + 32 + c) * 128) + gq;
        const bf16x8* Wp3 = (const bf16x8*)(W1 + (size_t)(cb2 + 48 + c) * 128) + gq;
        f32x4 a0 = zero, a1 = zero, a2 = zero, a3 = zero;
#pragma unroll
        for (int k = 0; k < 4; k++) {
            a0 = __builtin_amdgcn_mfma_f32_16x16x32_bf16(af[k], Wp0[k * 4], a0, 0, 0, 0);
            a1 = __builtin_amdgcn_mfma_f32_16x16x32_bf16(af[k], Wp1[k * 4], a1, 0, 0, 0);
            a2 = __builtin_amdgcn_mfma_f32_16x16x32_bf16(af[k], Wp2[k * 4], a2, 0, 0, 0);
            a3 = __builtin_amdgcn_mfma_f32_16x16x32_bf16(af[k], Wp3[k * 4], a3, 0, 0, 0);
        }
#pragma unroll
        for (int r = 0; r < 4; r++) {
            H[gq * 4 + r][cb2 + c]      = (bf16)gelu_f(a0[r] + bf1[cb2 + c]);
            H[gq * 4 + r][cb2 + 16 + c] = (bf16)gelu_f(a1[r] + bf1[cb2 + 16 + c]);
            H[gq * 4 + r][cb2 + 32 + c] = (bf16)gelu_f(a2[r] + bf1[cb2 + 32 + c]);
            H[gq * 4 + r][cb2 + 48 + c] = (bf16)gelu_f(a3[r] + bf1[cb2 + 48 + c]);
        }
    }
    __syncthreads();
    // Phase 3: ff2 (K=256, N=128). Wave wv cols w*32 (2 tiles).
    {
        int cb = w * 32;
        bf16x8 af[8];
#pragma unroll
        for (int k = 0; k < 8; k++)
            af[k] = *(const bf16x8*)&H[c][k * 32 + gq * 8];
        const bf16x8* Wp0 = (const bf16x8*)(W2 + (size_t)(cb + c) * 256) + gq;
        const bf16x8* Wp1 = (const bf16x8*)(W2 + (size_t)(cb + 16 + c) * 256) + gq;
        f32x4 a0 = zero, a1 = zero;
#pragma unroll
        for (int k = 0; k < 8; k++) {
            a0 = __builtin_amdgcn_mfma_f32_16x16x32_bf16(af[k], Wp0[k * 4], a0, 0, 0, 0);
            a1 = __builtin_amdgcn_mfma_f32_16x16x32_bf16(af[k], Wp1[k * 4], a1, 0, 0, 0);
        }
#pragma unroll
        for (int r = 0; r < 4; r++) {
            S[gq * 4 + r][cb + c] = a0[r] + bf2[cb + c];
            S[gq * 4 + r][cb + 16 + c] = a1[r] + bf2[cb + 16 + c];
        }
    }
    __syncthreads();
    // Epilogue 3: + X1 residual, LN2 -> global
    {
        int row = tid >> 4, cg_ = tid & 15;
        float v[8];
#pragma unroll
        for (int j = 0; j < 8; j++)
            v[j] = S[row][cg_ * 8 + j] + X1f[row][cg_ * 8 + j];
        float s = 0.0f;
#pragma unroll
        for (int j = 0; j < 8; j++) s += v[j];
        s += __shfl_xor(s, 1); s += __shfl_xor(s, 2);
        s += __shfl_xor(s, 4); s += __shfl_xor(s, 8);
        float mean = s * (1.0f / 128.0f);
        float vs = 0.0f;
#pragma unroll
        for (int j = 0; j < 8; j++) { float d = v[j] - mean; vs += d * d; }
        vs += __shfl_xor(vs, 1); vs += __shfl_xor(vs, 2);
        vs += __shfl_xor(vs, 4); vs += __shfl_xor(vs, 8);
        float rstd = rsqrtf(vs * (1.0f / 128.0f) + 1e-5f);
        size_t grow = (size_t)(blk * 16 + row);
        float y[8];
#pragma unroll
        for (int j = 0; j < 8; j++) {
            int col = cg_ * 8 + j;
            y[j] = (v[j] - mean) * rstd * g2[col] + be2[col];
        }
        float4* of = (float4*)(X0out + grow * 128 + cg_ * 8);
        of[0] = (float4){y[0], y[1], y[2], y[3]};
        of[1] = (float4){y[4], y[5], y[6], y[7]};
        bf16x8 o;
#pragma unroll
        for (int e = 0; e < 8; e++) o[e] = (bf16)y[e];
        *(bf16x8*)(X0hout + grow * 128 + cg_ * 8) = o;
    }
}

// Cross KV-projection (depends on final X0h), grid 512.
__global__ __launch_bounds__(256) void k_kv(
    const bf16* __restrict__ X0h, const bf16* __restrict__ Wkv,
    const float* __restrict__ bkv, bf16* __restrict__ Kh,
    bf16* __restrict__ Vth) {
    gemm4_body(blockIdx.x, X0h, Wkv, bkv, nullptr, Kh, Vth, 256, 128, 3, 1.0f);
}

// ---------------------------------------------------------------------------
// Cross tail: 16 rows/block, grid 512.
__global__ __launch_bounds__(256) void k_cross_tail(
    const bf16* __restrict__ ATTh, const bf16* __restrict__ Wo,
    const float* __restrict__ bo, const float* __restrict__ semb,
    const float* __restrict__ g1, const float* __restrict__ be1,
    const bf16* __restrict__ X0h, const bf16* __restrict__ W1,
    const float* __restrict__ bf1, const bf16* __restrict__ W2,
    const float* __restrict__ bf2, const float* __restrict__ g2,
    const float* __restrict__ be2, float* __restrict__ outp) {
    __shared__ float S[16][132];
    __shared__ bf16 s1h[16][136];
    __shared__ bf16 H[16][520];
    int tid = threadIdx.x;
    int w = tid >> 6, lane = tid & 63;
    int c = lane & 15, gq = lane >> 4;
    int blk = blockIdx.x;
    const f32x4 zero = {0, 0, 0, 0};

    // Prefetch CAT second-half A-frags from X0h (xt-order remap)
    bf16x8 agl[4];
    {
        int tr = blk * 16 + c;
        int b = tr >> 11, t = (tr >> 3) & 255, n = tr & 7;
        const bf16* xrow = X0h + ((size_t)((b * 8 + n) * 256 + t)) * 128;
#pragma unroll
        for (int k = 0; k < 4; k++)
            agl[k] = *(const bf16x8*)(xrow + k * 32 + gq * 8);
    }

    // Phase 1: outproj (K=128, N=128). Wave wv cols w*32.
    {
        int cb = w * 32;
        const bf16x8* Ap  = (const bf16x8*)(ATTh + (size_t)(blk * 16 + c) * 128) + gq;
        const bf16x8* Wp0 = (const bf16x8*)(Wo + (size_t)(cb + c) * 128) + gq;
        const bf16x8* Wp1 = (const bf16x8*)(Wo + (size_t)(cb + 16 + c) * 128) + gq;
        f32x4 a0 = zero, a1 = zero;
#pragma unroll
        for (int k = 0; k < 4; k++) {
            bf16x8 av = Ap[k * 4];
            a0 = __builtin_amdgcn_mfma_f32_16x16x32_bf16(av, Wp0[k * 4], a0, 0, 0, 0);
            a1 = __builtin_amdgcn_mfma_f32_16x16x32_bf16(av, Wp1[k * 4], a1, 0, 0, 0);
        }
#pragma unroll
        for (int r = 0; r < 4; r++) {
            S[gq * 4 + r][cb + c] = a0[r] + bo[cb + c];
            S[gq * 4 + r][cb + 16 + c] = a1[r] + bo[cb + 16 + c];
        }
    }
    __syncthreads();
    // Epilogue 1: + semb residual, LN1 -> s1h
    {
        int row = tid >> 4, cg_ = tid & 15;
        float v[8];
        const float4* rp = (const float4*)(semb + (size_t)(blk * 16 + row) * 128 + cg_ * 8);
        float4 r0 = rp[0], r1 = rp[1];
        v[0] = S[row][cg_ * 8 + 0] + r0.x; v[1] = S[row][cg_ * 8 + 1] + r0.y;
        v[2] = S[row][cg_ * 8 + 2] + r0.z; v[3] = S[row][cg_ * 8 + 3] + r0.w;
        v[4] = S[row][cg_ * 8 + 4] + r1.x; v[5] = S[row][cg_ * 8 + 5] + r1.y;
        v[6] = S[row][cg_ * 8 + 6] + r1.z; v[7] = S[row][cg_ * 8 + 7] + r1.w;
        float s = 0.0f;
#pragma unroll
        for (int j = 0; j < 8; j++) s += v[j];
        s += __shfl_xor(s, 1); s += __shfl_xor(s, 2);
        s += __shfl_xor(s, 4); s += __shfl_xor(s, 8);
        float mean = s * (1.0f / 128.0f);
        float vs = 0.0f;
#pragma unroll
        for (int j = 0; j < 8; j++) { float d = v[j] - mean; vs += d * d; }
        vs += __shfl_xor(vs, 1); vs += __shfl_xor(vs, 2);
        vs += __shfl_xor(vs, 4); vs += __shfl_xor(vs, 8);
        float rstd = rsqrtf(vs * (1.0f / 128.0f) + 1e-5f);
#pragma unroll
        for (int j = 0; j < 8; j++) {
            int col = cg_ * 8 + j;
            s1h[row][col] = (bf16)((v[j] - mean) * rstd * g1[col] + be1[col]);
        }
    }
    __syncthreads();
    // Phase 2: ff1 (K=256 concat, N=512). Wave wv cols w*128 (2x4 tiles).
    {
        bf16x8 afl[4];
#pragma unroll
        for (int k = 0; k < 4; k++)
            afl[k] = *(const bf16x8*)&s1h[c][k * 32 + gq * 8];
#pragma unroll
        for (int ci = 0; ci < 2; ci++) {
            int cb2 = w * 128 + ci * 64;
            const bf16x8* Wp0 = (const bf16x8*)(W1 + (size_t)(cb2 + c) * 256) + gq;
            const bf16x8* Wp1 = (const bf16x8*)(W1 + (size_t)(cb2 + 16 + c) * 256) + gq;
            const bf16x8* Wp2 = (const bf16x8*)(W1 + (size_t)(cb2 + 32 + c) * 256) + gq;
            const bf16x8* Wp3 = (const bf16x8*)(W1 + (size_t)(cb2 + 48 + c) * 256) + gq;
            f32x4 a0 = zero, a1 = zero, a2 = zero, a3 = zero;
#pragma unroll
            for (int k = 0; k < 8; k++) {
                bf16x8 av = (k < 4) ? afl[k] : agl[k - 4];
                a0 = __builtin_amdgcn_mfma_f32_16x16x32_bf16(av, Wp0[k * 4], a0, 0, 0, 0);
                a1 = __builtin_amdgcn_mfma_f32_16x16x32_bf16(av, Wp1[k * 4], a1, 0, 0, 0);
                a2 = __builtin_amdgcn_mfma_f32_16x16x32_bf16(av, Wp2[k * 4], a2, 0, 0, 0);
                a3 = __builtin_amdgcn_mfma_f32_16x16x32_bf16(av, Wp3[k * 4], a3, 0, 0, 0);
            }
#pragma unroll
            for (int r = 0; r < 4; r++) {
                H[gq * 4 + r][cb2 + c]      = (bf16)gelu_f(a0[r] + bf1[cb2 + c]);
                H[gq * 4 + r][cb2 + 16 + c] = (bf16)gelu_f(a1[r] + bf1[cb2 + 16 + c]);
                H[gq * 4 + r][cb2 + 32 + c] = (bf16)gelu_f(a2[r] + bf1[cb2 + 32 + c]);
                H[gq * 4 + r][cb2 + 48 + c] = (bf16)gelu_f(a3[r] + bf1[cb2 + 48 + c]);
            }
        }
    }
    __syncthreads();
    // Phase 3: ff2 (K=512, N=128). Wave wv cols w*32 (2 tiles).
    {
        int cb = w * 32;
        const bf16x8* Wp0 = (const bf16x8*)(W2 + (size_t)(cb + c) * 512) + gq;
        const bf16x8* Wp1 = (const bf16x8*)(W2 + (size_t)(cb + 16 + c) * 512) + gq;
        f32x4 a0 = zero, a1 = zero;
#pragma unroll
        for (int k = 0; k < 16; k++) {
            bf16x8 av = *(const bf16x8*)&H[c][k * 32 + gq * 8];
            a0 = __builtin_amdgcn_mfma_f32_16x16x32_bf16(av, Wp0[k * 4], a0, 0, 0, 0);
            a1 = __builtin_amdgcn_mfma_f32_16x16x32_bf16(av, Wp1[k * 4], a1, 0, 0, 0);
        }
#pragma unroll
        for (int r = 0; r < 4; r++) {
            S[gq * 4 + r][cb + c] = a0[r] + bf2[cb + c];
            S[gq * 4 + r][cb + 16 + c] = a1[r] + bf2[cb + 16 + c];
        }
    }
    __syncthreads();
    // Epilogue 3: + s1 residual, final LN -> outp
    {
        int row = tid >> 4, cg_ = tid & 15;
        float v[8];
#pragma unroll
        for (int j = 0; j < 8; j++)
            v[j] = S[row][cg_ * 8 + j] + (float)s1h[row][cg_ * 8 + j];
        float s = 0.0f;
#pragma unroll
        for (int j = 0; j < 8; j++) s += v[j];
        s += __shfl_xor(s, 1); s += __shfl_xor(s, 2);
        s += __shfl_xor(s, 4); s += __shfl_xor(s, 8);
        float mean = s * (1.0f / 128.0f);
        float vs = 0.0f;
#pragma unroll
        for (int j = 0; j < 8; j++) { float d = v[j] - mean; vs += d * d; }
        vs += __shfl_xor(vs, 1); vs += __shfl_xor(vs, 2);
        vs += __shfl_xor(vs, 4); vs += __shfl_xor(vs, 8);
        float rstd = rsqrtf(vs * (1.0f / 128.0f) + 1e-5f);
        float y[8];
#pragma unroll
        for (int j = 0; j < 8; j++) {
            int col = cg_ * 8 + j;
            y[j] = (v[j] - mean) * rstd * g2[col] + be2[col];
        }
        float4* of = (float4*)(outp + (size_t)(blk * 16 + row) * 128 + cg_ * 8);
        of[0] = (float4){y[0], y[1], y[2], y[3]};
        of[1] = (float4){y[4], y[5], y[6], y[7]};
    }
}

// ---------------------------------------------------------------------------
// Cross attention: 64 q/wave, 4-way key-split, LDS combine. Q pre-scaled.
__global__ __launch_bounds__(256) void k_mattn(
    const bf16* __restrict__ Qh, const bf16* __restrict__ Kh,
    const bf16* __restrict__ Vth, bf16* __restrict__ ATTh,
    int Lq, int Lk, int NSH) {
    int sh = blockIdx.x % NSH;
    int qblk = blockIdx.x / NSH;
    int wv = threadIdx.x >> 6;
    int lane = threadIdx.x & 63;
    int c = lane & 15, g = lane >> 4;
    int q0 = qblk * 64;

    __shared__ float O_lds[4][64][36];
    __shared__ float L_lds[4][64];

    const f32x4 zero = {0, 0, 0, 0};

    bf16x8 bq[4];
#pragma unroll
    for (int qt = 0; qt < 4; qt++)
        bq[qt] = *(const bf16x8*)(
            Qh + ((size_t)sh * Lq + q0 + qt * 16 + c) * 32 + g * 8);

    int klen = Lk >> 2;
    int kbeg = wv * klen;
    const bf16* Kbase = Kh + (size_t)sh * Lk * 32 + (size_t)kbeg * 32;
    const bf16* Vbase = Vth + (size_t)sh * 32 * Lk + kbeg;

    f32x4 oT[4][2];
#pragma unroll
    for (int qt = 0; qt < 4; qt++) { oT[qt][0] = zero; oT[qt][1] = zero; }
    float lsum[4] = {0, 0, 0, 0};

    int ntiles = klen >> 5;
    bf16x8 ka = *(const bf16x8*)(Kbase + (size_t)c * 32 + g * 8);
    bf16x8 kb = *(const bf16x8*)(Kbase + (size_t)(16 + c) * 32 + g * 8);
    bf16x4 va0 = *(const bf16x4*)(Vbase + (size_t)c * Lk + g * 4);
    bf16x4 va1 = *(const bf16x4*)(Vbase + (size_t)c * Lk + 16 + g * 4);
    bf16x4 vb0 = *(const bf16x4*)(Vbase + (size_t)(16 + c) * Lk + g * 4);
    bf16x4 vb1 = *(const bf16x4*)(Vbase + (size_t)(16 + c) * Lk + 16 + g * 4);

    for (int t = 0; t < ntiles; t++) {
        bf16x8 cka = ka, ckb = kb;
        bf16x4 cva0 = va0, cva1 = va1, cvb0 = vb0, cvb1 = vb1;
        int nk0 = ((t + 1 < ntiles) ? (t + 1) : t) << 5;
        ka = *(const bf16x8*)(Kbase + (size_t)(nk0 + c) * 32 + g * 8);
        kb = *(const bf16x8*)(Kbase + (size_t)(nk0 + 16 + c) * 32 + g * 8);
        va0 = *(const bf16x4*)(Vbase + (size_t)c * Lk + nk0 + g * 4);
        va1 = *(const bf16x4*)(Vbase + (size_t)c * Lk + nk0 + 16 + g * 4);
        vb0 = *(const bf16x4*)(Vbase + (size_t)(16 + c) * Lk + nk0 + g * 4);
        vb1 = *(const bf16x4*)(Vbase + (size_t)(16 + c) * Lk + nk0 + 16 + g * 4);

#pragma unroll
        for (int qt = 0; qt < 4; qt++) {
            f32x4 s0 = __builtin_amdgcn_mfma_f32_16x16x32_bf16(cka, bq[qt], zero, 0, 0, 0);
            f32x4 s1 = __builtin_amdgcn_mfma_f32_16x16x32_bf16(ckb, bq[qt], zero, 0, 0, 0);
            bf16x4 p0, p1;
#pragma unroll
            for (int r = 0; r < 4; r++) {
                float e0 = exp2_fast(s0[r]);
                float e1 = exp2_fast(s1[r]);
                lsum[qt] += e0 + e1;
                p0[r] = (bf16)e0;
                p1[r] = (bf16)e1;
            }
            oT[qt][0] = pv_mfma16(cva0, p0, oT[qt][0]);
            oT[qt][0] = pv_mfma16(cva1, p1, oT[qt][0]);
            oT[qt][1] = pv_mfma16(cvb0, p0, oT[qt][1]);
            oT[qt][1] = pv_mfma16(cvb1, p1, oT[qt][1]);
        }
    }

#pragma unroll
    for (int qt = 0; qt < 4; qt++) {
        float s = lsum[qt];
        s += __shfl_xor(s, 16);
        s += __shfl_xor(s, 32);
        if (g == 0) L_lds[wv][qt * 16 + c] = s;
        *(f32x4*)&O_lds[wv][qt * 16 + c][g * 4] = oT[qt][0];
        *(f32x4*)&O_lds[wv][qt * 16 + c][16 + g * 4] = oT[qt][1];
    }
    __syncthreads();

    int tid = threadIdx.x;
    int ql = tid >> 2, dq = (tid & 3) * 8;
    float ltot = L_lds[0][ql] + L_lds[1][ql] + L_lds[2][ql] + L_lds[3][ql];
    float inv = 1.0f / ltot;
    float acc[8];
#pragma unroll
    for (int j = 0; j < 8; j++) acc[j] = 0.0f;
#pragma unroll
    for (int w = 0; w < 4; w++) {
        const float* p = &O_lds[w][ql][dq];
#pragma unroll
        for (int j = 0; j < 8; j++) acc[j] += p[j];
    }
    int h = sh & 3, sb = sh >> 2;
    bf16x8 o;
#pragma unroll
    for (int j = 0; j < 8; j++) o[j] = (bf16)(acc[j] * inv);
    *(bf16x8*)(ATTh + ((size_t)sb * Lq + q0 + ql) * 128 + h * 32 + dq) = o;
}

// ---------------------------------------------------------------------------
extern "C" void kernel_launch(void* const* d_in, const int* in_sizes, int n_in,
                              void* d_out, int out_size, void* d_ws, size_t ws_size,
                              hipStream_t stream) {
    const float* vs       = (const float*)d_in[0];
    const float* semb     = (const float*)d_in[1];
    const float* r5       = (const float*)d_in[2];
    const float* A55      = (const float*)d_in[3];
    const float* bl_bias  = (const float*)d_in[4];
    const float* nl_W1    = (const float*)d_in[5];
    const float* nl_b1    = (const float*)d_in[6];
    const float* nl_W2    = (const float*)d_in[7];
    const float* nl_b2    = (const float*)d_in[8];
    const float* mlp_W1   = (const float*)d_in[9];
    const float* mlp_b1   = (const float*)d_in[10];
    const float* mlp_W2   = (const float*)d_in[11];
    const float* mlp_b2   = (const float*)d_in[12];
    const float* mlp_ln_g = (const float*)d_in[13];
    const float* mlp_ln_b = (const float*)d_in[14];
    const float* enc_qkv_W = (const float*)d_in[15];
    const float* enc_qkv_b = (const float*)d_in[16];
    const float* enc_out_W = (const float*)d_in[17];
    const float* enc_out_b = (const float*)d_in[18];
    const float* enc_ln1_g = (const float*)d_in[19];
    const float* enc_ln1_b = (const float*)d_in[20];
    const float* enc_ff_W1 = (const float*)d_in[21];
    const float* enc_ff_b1 = (const float*)d_in[22];
    const float* enc_ff_W2 = (const float*)d_in[23];
    const float* enc_ff_b2 = (const float*)d_in[24];
    const float* enc_ln2_g = (const float*)d_in[25];
    const float* enc_ln2_b = (const float*)d_in[26];
    const float* ca_Wq = (const float*)d_in[27];
    const float* ca_bq = (const float*)d_in[28];
    const float* ca_Wk = (const float*)d_in[29];
    const float* ca_bk = (const float*)d_in[30];
    const float* ca_Wv = (const float*)d_in[31];
    const float* ca_bv = (const float*)d_in[32];
    const float* ca_Wo = (const float*)d_in[33];
    const float* ca_bo = (const float*)d_in[34];
    const float* ca_ln1_g = (const float*)d_in[35];
    const float* ca_ln1_b = (const float*)d_in[36];
    const float* ca_ff_W1 = (const float*)d_in[37];
    const float* ca_ff_b1 = (const float*)d_in[38];
    const float* ca_ff_W2 = (const float*)d_in[39];
    const float* ca_ff_b2 = (const float*)d_in[40];
    const float* ca_ln2_g = (const float*)d_in[41];
    const float* ca_ln2_b = (const float*)d_in[42];
    float* out = (float*)d_out;

    // Workspace layout (byte offsets, 256-aligned)
    char* base = (char*)d_ws;
    float* X0    = (float*)(base + 163840);     //   4 MB
    char*  QKVr  = base + 8552448;              //   6 MB region (cross QKV)
    bf16*  Wpk   = (bf16*) (base + 25329664);   //   1 MB
    float* bpk   = (float*)(base + 26411008);   //   1 KB
    bf16*  X0h   = (bf16*) (base + 26412032);   //   2 MB
    bf16*  sembh = (bf16*) (base + 30606336);   //   2 MB
    bf16*  ATTh  = (bf16*) (base + 32703488);   //   2 MB
    bf16*  Qh    = (bf16*)QKVr;                 //   2 MB
    bf16*  Kh    = (bf16*)(QKVr + 2097152);     //   2 MB
    bf16*  Vth   = (bf16*)(QKVr + 4194304);     //   2 MB

    // 1. pack + b1(inline) + features + mlp + LN + PE (one dispatch)
    k_mlp_prep<<<dim3(512), dim3(256), 0, stream>>>(
        vs, mlp_W1, mlp_b1, mlp_W2, mlp_b2, mlp_ln_g, mlp_ln_b,
        r5, A55, bl_bias, nl_W1, nl_b1, nl_W2, nl_b2,
        enc_qkv_W, enc_out_W, enc_ff_W1, enc_ff_W2,
        ca_Wq, ca_Wk, ca_Wv, ca_Wo, ca_ff_W1, ca_ff_W2,
        semb, ca_bk, ca_bv,
        Wpk, sembh, bpk, X0, X0h);

    // 2-5. Encoder layers; layer-1 tail dispatch also runs cross Q-proj.
    for (int i = 0; i < LENC_; i++) {
        k_enc_attn<<<dim3(512), dim3(256), 0, stream>>>(
            X0h, Wpk + i * 49152, enc_qkv_b + i * 384, ATTh);
        int tgrid = (i == LENC_ - 1) ? 768 : 512;
        k_enc_tail<<<dim3(tgrid), dim3(256), 0, stream>>>(
            ATTh, Wpk + 98304 + i * 16384, enc_out_b + i * 128, X0,
            enc_ln1_g + i * 128, enc_ln1_b + i * 128,
            Wpk + 131072 + i * 32768, enc_ff_b1 + i * 256,
            Wpk + 196608 + i * 32768, enc_ff_b2 + i * 128,
            enc_ln2_g + i * 128, enc_ln2_b + i * 128, X0, X0h,
            sembh, Wpk + 262144, ca_bq, Qh);
    }

    // 6-8. Cross: KV -> attention -> fused tail -> out
    k_kv<<<dim3(512), dim3(256), 0, stream>>>(
        X0h, Wpk + 278528, bpk, Kh, Vth);
    k_mattn<<<dim3(512), dim3(256), 0, stream>>>(
        Qh, Kh, Vth, ATTh, 2048, 2048, 16);
    k_cross_tail<<<dim3(512), dim3(256), 0, stream>>>(
        ATTh, Wpk + 311296, ca_bo, semb, ca_ln1_g, ca_ln1_b, X0h,
        Wpk + 327680, ca_ff_b1, Wpk + 458752, ca_ff_b2,
        ca_ln2_g, ca_ln2_b, out);
}